// Round 1
// baseline (799.462 us; speedup 1.0000x reference)
//
#include <hip/hip_runtime.h>
#include <hip/hip_bf16.h>

typedef unsigned short u16;
typedef __attribute__((ext_vector_type(8))) short bf16x8;
typedef __attribute__((ext_vector_type(8))) unsigned short u16x8;
typedef __attribute__((ext_vector_type(4))) float f32x4;

#define MFMA16(a,b,c) __builtin_amdgcn_mfma_f32_16x16x32_bf16(a,b,c,0,0,0)

__device__ __forceinline__ u16 f2bf(float f) {
  union { float f; unsigned int u; } v; v.f = f;
  unsigned int r = v.u + 0x7fffu + ((v.u >> 16) & 1u);  // RNE, finite inputs
  return (u16)(r >> 16);
}
__device__ __forceinline__ float bf2f(u16 u) {
  union { unsigned int i; float f; } v; v.i = ((unsigned int)u) << 16; return v.f;
}

__device__ __forceinline__ void gld16(const void* g, void* l) {
  __builtin_amdgcn_global_load_lds((const __attribute__((address_space(1))) void*)g,
                                   (__attribute__((address_space(3))) void*)l, 16, 0, 0);
}

// ---------------- cast fp32 -> bf16 (4/thread) ----------------
__global__ void cast4(const float* __restrict__ in, u16* __restrict__ out, int n4) {
  int i = blockIdx.x * blockDim.x + threadIdx.x;
  if (i >= n4) return;
  float4 v = reinterpret_cast<const float4*>(in)[i];
  ushort4 o; o.x = f2bf(v.x); o.y = f2bf(v.y); o.z = f2bf(v.z); o.w = f2bf(v.w);
  reinterpret_cast<ushort4*>(out)[i] = o;
}

// ---------------- transpose-cast weight: out[n*K+k] = bf16(in[k*N+n]) ----------------
__global__ void tcast(const float* __restrict__ in, u16* __restrict__ out, int K, int N) {
  int idx = blockIdx.x * blockDim.x + threadIdx.x;
  if (idx >= K * N) return;
  int n = idx / K, k = idx - n * K;
  out[idx] = f2bf(in[(size_t)k * N + n]);
}

// ---------------- GEMM: C[M,N] = A[M,K] * Bt[N,K]^T + bias ----------------
// 128x128 tile, BK=32, 4 waves (2x2), m97-style global_load_lds staging.
// EPI 0: split q/k/v bf16 epilogue (N=2304). EPI 1: fp32 out (proj).
template<int EPI>
__launch_bounds__(256)
__global__ void gemm_bt(const u16* __restrict__ A, const u16* __restrict__ Bt,
                        const float* __restrict__ bias,
                        u16* __restrict__ oq, u16* __restrict__ ok, u16* __restrict__ ov,
                        float* __restrict__ of, int K) {
  __shared__ __align__(16) u16 As[128 * 32];
  __shared__ __align__(16) u16 Bs[128 * 32];
  const int tid = threadIdx.x;
  const int wave = tid >> 6, lane = tid & 63;
  const int c = lane & 15, g = lane >> 4;
  const int brow = blockIdx.y * 128, bcol = blockIdx.x * 128;
  const int wr = (wave >> 1) * 64, wc = (wave & 1) * 64;
  f32x4 acc[4][4] = {};
  // staging map: wave w covers rows [w*32, w*32+32) of both tiles
  const int srow = wave * 32 + (lane >> 2);
  const int scol = (lane & 3) * 8;
  const u16* agp0 = A  + (size_t)(brow + srow) * K + scol;
  const u16* agp1 = A  + (size_t)(brow + srow + 16) * K + scol;
  const u16* bgp0 = Bt + (size_t)(bcol + srow) * K + scol;
  const u16* bgp1 = Bt + (size_t)(bcol + srow + 16) * K + scol;
  u16* al0 = &As[wave * 1024];       u16* al1 = &As[wave * 1024 + 512];
  u16* bl0 = &Bs[wave * 1024];       u16* bl1 = &Bs[wave * 1024 + 512];
  for (int k0 = 0; k0 < K; k0 += 32) {
    __syncthreads();
    gld16(agp0 + k0, al0);
    gld16(agp1 + k0, al1);
    gld16(bgp0 + k0, bl0);
    gld16(bgp1 + k0, bl1);
    __syncthreads();
    bf16x8 af[4], bfr[4];
    #pragma unroll
    for (int mi = 0; mi < 4; ++mi)
      af[mi] = *reinterpret_cast<const bf16x8*>(&As[(wr + mi * 16 + c) * 32 + g * 8]);
    #pragma unroll
    for (int ni = 0; ni < 4; ++ni)
      bfr[ni] = *reinterpret_cast<const bf16x8*>(&Bs[(wc + ni * 16 + c) * 32 + g * 8]);
    #pragma unroll
    for (int mi = 0; mi < 4; ++mi)
      #pragma unroll
      for (int ni = 0; ni < 4; ++ni)
        acc[mi][ni] = MFMA16(af[mi], bfr[ni], acc[mi][ni]);
  }
  #pragma unroll
  for (int mi = 0; mi < 4; ++mi) {
    #pragma unroll
    for (int ni = 0; ni < 4; ++ni) {
      const int col = bcol + wc + ni * 16 + c;
      const float bz = bias[col];
      #pragma unroll
      for (int i = 0; i < 4; ++i) {
        const int row = brow + wr + mi * 16 + g * 4 + i;
        float v = acc[mi][ni][i] + bz;
        if (EPI == 0) {
          if (col < 768)       oq[(size_t)row * 768 + col]        = f2bf(v);
          else if (col < 1536) ok[(size_t)row * 768 + col - 768]  = f2bf(v);
          else                 ov[(size_t)row * 768 + col - 1536] = f2bf(v);
        } else {
          of[(size_t)row * 768 + col] = v;
        }
      }
    }
  }
}

// ---------------- 2x2 max-pool on q (bf16), rows 16384 -> 4096 ----------------
__global__ void qpool(const u16* __restrict__ qf, u16* __restrict__ qp) {
  int idx = blockIdx.x * blockDim.x + threadIdx.x;
  if (idx >= 4096 * 96) return;
  int r = idx / 96, cc = (idx - r * 96) * 8;
  int b = r >> 10, ij = r & 1023, ii = ij >> 5, jj = ij & 31;
  const size_t base = ((size_t)b * 4096 + (size_t)ii * 128 + jj * 2) * 768 + cc;
  u16x8 x0 = *reinterpret_cast<const u16x8*>(qf + base);
  u16x8 x1 = *reinterpret_cast<const u16x8*>(qf + base + 768);
  u16x8 x2 = *reinterpret_cast<const u16x8*>(qf + base + 64 * 768);
  u16x8 x3 = *reinterpret_cast<const u16x8*>(qf + base + 65 * 768);
  u16x8 o;
  #pragma unroll
  for (int e = 0; e < 8; ++e) {
    u16 rb = x0[e]; float mv = bf2f(rb);
    float f1 = bf2f(x1[e]); if (f1 > mv) { mv = f1; rb = x1[e]; }
    float f2 = bf2f(x2[e]); if (f2 > mv) { mv = f2; rb = x2[e]; }
    float f3 = bf2f(x3[e]); if (f3 > mv) { mv = f3; rb = x3[e]; }
    o[e] = rb;
  }
  *reinterpret_cast<u16x8*>(qp + (size_t)r * 768 + cc) = o;
}

// ---------------- flash attention ----------------
// grid 512: blk = (b*8+h)*16 + qt. 4 waves, wave w owns q rows [qt*64+w*16, +16).
// K-tiles of 32 keys; Ks[32][96] natural, Vt[96][32] transposed, P via per-wave LDS.
__launch_bounds__(256)
__global__ void flash(const u16* __restrict__ Qp, const u16* __restrict__ Kb,
                      const u16* __restrict__ Vb, u16* __restrict__ Ob) {
  const int blk = blockIdx.x;
  const int qt = blk & 15, bh = blk >> 4;
  const int b = bh >> 3, h = bh & 7;
  __shared__ __align__(16) u16 Ks[32 * 96];
  __shared__ __align__(16) u16 Vt[96 * 32];
  __shared__ __align__(16) u16 Pl[4 * 16 * 32];
  const int tid = threadIdx.x, w = tid >> 6, lane = tid & 63;
  const int c = lane & 15, g = lane >> 4;
  const u16* qb = Qp + (size_t)(b * 1024 + qt * 64 + w * 16 + c) * 768 + h * 96;
  bf16x8 qf[3];
  #pragma unroll
  for (int kc = 0; kc < 3; ++kc)
    qf[kc] = *reinterpret_cast<const bf16x8*>(qb + kc * 32 + g * 8);
  float m[4], l[4];
  f32x4 acc[6] = {};
  #pragma unroll
  for (int i = 0; i < 4; ++i) { m[i] = -1e30f; l[i] = 0.f; }
  const u16* kb = Kb + (size_t)b * 4096 * 768 + h * 96;
  const u16* vb = Vb + (size_t)b * 4096 * 768 + h * 96;
  const float scale = 0.1020620726159658f;  // 96^-0.5
  const float L2E = 1.44269504f;
  for (int kt = 0; kt < 128; ++kt) {
    __syncthreads();
    for (int ch = tid; ch < 384; ch += 256) {          // Ks: 32 keys x 12 chunks of 8
      int key = ch / 12, off = (ch - key * 12) * 8;
      *reinterpret_cast<uint4*>(&Ks[key * 96 + off]) =
        *reinterpret_cast<const uint4*>(kb + (size_t)(kt * 32 + key) * 768 + off);
    }
    for (int e = tid; e < 3072; e += 256) {            // Vt transpose
      int key = e / 96, d = e - key * 96;
      Vt[d * 32 + key] = vb[(size_t)(kt * 32 + key) * 768 + d];
    }
    __syncthreads();
    f32x4 s0 = {0.f, 0.f, 0.f, 0.f}, s1 = {0.f, 0.f, 0.f, 0.f};
    #pragma unroll
    for (int kc = 0; kc < 3; ++kc) {
      bf16x8 k0 = *reinterpret_cast<const bf16x8*>(&Ks[c * 96 + kc * 32 + g * 8]);
      bf16x8 k1 = *reinterpret_cast<const bf16x8*>(&Ks[(16 + c) * 96 + kc * 32 + g * 8]);
      s0 = MFMA16(qf[kc], k0, s0);
      s1 = MFMA16(qf[kc], k1, s1);
    }
    float esc[4], p0[4], p1[4];
    #pragma unroll
    for (int i = 0; i < 4; ++i) {
      float a0 = s0[i] * scale, a1 = s1[i] * scale;
      float t = fmaxf(a0, a1);
      t = fmaxf(t, __shfl_xor(t, 1));
      t = fmaxf(t, __shfl_xor(t, 2));
      t = fmaxf(t, __shfl_xor(t, 4));
      t = fmaxf(t, __shfl_xor(t, 8));
      float mn = fmaxf(m[i], t);
      esc[i] = exp2f((m[i] - mn) * L2E);
      p0[i] = exp2f((a0 - mn) * L2E);
      p1[i] = exp2f((a1 - mn) * L2E);
      float rs = p0[i] + p1[i];
      rs += __shfl_xor(rs, 1);
      rs += __shfl_xor(rs, 2);
      rs += __shfl_xor(rs, 4);
      rs += __shfl_xor(rs, 8);
      l[i] = l[i] * esc[i] + rs;
      m[i] = mn;
    }
    #pragma unroll
    for (int dc = 0; dc < 6; ++dc)
      #pragma unroll
      for (int i = 0; i < 4; ++i)
        acc[dc][i] *= esc[i];
    #pragma unroll
    for (int i = 0; i < 4; ++i) {
      Pl[(w * 16 + g * 4 + i) * 32 + c]      = f2bf(p0[i]);
      Pl[(w * 16 + g * 4 + i) * 32 + 16 + c] = f2bf(p1[i]);
    }
    __syncthreads();   // cross-lane P visibility (safe baseline)
    bf16x8 pf = *reinterpret_cast<const bf16x8*>(&Pl[(w * 16 + c) * 32 + g * 8]);
    #pragma unroll
    for (int dc = 0; dc < 6; ++dc) {
      bf16x8 vf = *reinterpret_cast<const bf16x8*>(&Vt[(dc * 16 + c) * 32 + g * 8]);
      acc[dc] = MFMA16(pf, vf, acc[dc]);
    }
  }
  u16* ob = Ob + (size_t)(b * 1024 + qt * 64 + w * 16) * 768 + h * 96;
  #pragma unroll
  for (int dc = 0; dc < 6; ++dc)
    #pragma unroll
    for (int i = 0; i < 4; ++i) {
      float o = acc[dc][i] / l[i];
      ob[(size_t)(g * 4 + i) * 768 + dc * 16 + c] = f2bf(o);
    }
}

extern "C" void kernel_launch(void* const* d_in, const int* in_sizes, int n_in,
                              void* d_out, int out_size, void* d_ws, size_t ws_size,
                              hipStream_t stream) {
  const float* hs     = (const float*)d_in[0];   // (4,64,64,384)
  const float* qkv_w  = (const float*)d_in[1];   // (384,2304)
  const float* qkv_b  = (const float*)d_in[2];   // (2304)
  const float* proj_w = (const float*)d_in[3];   // (768,768)
  const float* proj_b = (const float*)d_in[4];   // (768)
  float* out = (float*)d_out;                    // (4,32,32,768) fp32

  u16* hs_bf  = (u16*)d_ws;                 // 6291456
  u16* qkvwT  = hs_bf  + 6291456;           // 884736  (2304 x 384)
  u16* projwT = qkvwT  + 884736;            // 589824  (768 x 768)
  u16* qfull  = projwT + 589824;            // 16384 x 768
  u16* kbuf   = qfull  + 12582912;          // 16384 x 768
  u16* vbuf   = kbuf   + 12582912;          // 16384 x 768
  u16* qpol   = vbuf   + 12582912;          // 4096 x 768
  u16* aout   = qpol   + 3145728;           // 4096 x 768

  cast4<<<6144, 256, 0, stream>>>(hs, hs_bf, 1572864);
  tcast<<<3456, 256, 0, stream>>>(qkv_w, qkvwT, 384, 2304);
  tcast<<<2304, 256, 0, stream>>>(proj_w, projwT, 768, 768);

  gemm_bt<0><<<dim3(18, 128), 256, 0, stream>>>(hs_bf, qkvwT, qkv_b,
                                                qfull, kbuf, vbuf, nullptr, 384);
  qpool<<<1536, 256, 0, stream>>>(qfull, qpol);
  flash<<<512, 256, 0, stream>>>(qpol, kbuf, vbuf, aout);
  gemm_bt<1><<<dim3(6, 32), 256, 0, stream>>>(aout, projwT, proj_b,
                                              nullptr, nullptr, nullptr, out, 768);
}

// Round 3
// 286.206 us; speedup vs baseline: 2.7933x; 2.7933x over previous
//
#include <hip/hip_runtime.h>
#include <hip/hip_bf16.h>

typedef unsigned short u16;
typedef __attribute__((ext_vector_type(8))) short bf16x8;
typedef __attribute__((ext_vector_type(8))) unsigned short u16x8;
typedef __attribute__((ext_vector_type(4))) float f32x4;

#define MFMA16(a,b,c) __builtin_amdgcn_mfma_f32_16x16x32_bf16(a,b,c,0,0,0)

__device__ __forceinline__ u16 f2bf(float f) {
  union { float f; unsigned int u; } v; v.f = f;
  unsigned int r = v.u + 0x7fffu + ((v.u >> 16) & 1u);  // RNE, finite inputs
  return (u16)(r >> 16);
}
__device__ __forceinline__ float bf2f(u16 u) {
  union { unsigned int i; float f; } v; v.i = ((unsigned int)u) << 16; return v.f;
}

__device__ __forceinline__ void gld16(const void* g, void* l) {
  __builtin_amdgcn_global_load_lds((const __attribute__((address_space(1))) void*)g,
                                   (__attribute__((address_space(3))) void*)l, 16, 0, 0);
}

// ---------------- cast fp32 -> bf16 (4/thread) ----------------
__global__ void cast4(const float* __restrict__ in, u16* __restrict__ out, int n4) {
  int i = blockIdx.x * blockDim.x + threadIdx.x;
  if (i >= n4) return;
  float4 v = reinterpret_cast<const float4*>(in)[i];
  ushort4 o; o.x = f2bf(v.x); o.y = f2bf(v.y); o.z = f2bf(v.z); o.w = f2bf(v.w);
  reinterpret_cast<ushort4*>(out)[i] = o;
}

// ---------------- transpose-cast weight: out[n*K+k] = bf16(in[k*N+n]) ----------------
__global__ void tcast(const float* __restrict__ in, u16* __restrict__ out, int K, int N) {
  int idx = blockIdx.x * blockDim.x + threadIdx.x;
  if (idx >= K * N) return;
  int n = idx / K, k = idx - n * K;
  out[idx] = f2bf(in[(size_t)k * N + n]);
}

// ---------------- GEMM: C[M,N] = A[M,K] * Bt[N,K]^T + bias ----------------
template<int EPI>
__launch_bounds__(256)
__global__ void gemm_bt(const u16* __restrict__ A, const u16* __restrict__ Bt,
                        const float* __restrict__ bias,
                        u16* __restrict__ oq, u16* __restrict__ ok, u16* __restrict__ ov,
                        float* __restrict__ of, int K) {
  __shared__ __align__(16) u16 As[128 * 32];
  __shared__ __align__(16) u16 Bs[128 * 32];
  const int tid = threadIdx.x;
  const int wave = tid >> 6, lane = tid & 63;
  const int c = lane & 15, g = lane >> 4;
  const int brow = blockIdx.y * 128, bcol = blockIdx.x * 128;
  const int wr = (wave >> 1) * 64, wc = (wave & 1) * 64;
  f32x4 acc[4][4] = {};
  const int srow = wave * 32 + (lane >> 2);
  const int scol = (lane & 3) * 8;
  const u16* agp0 = A  + (size_t)(brow + srow) * K + scol;
  const u16* agp1 = A  + (size_t)(brow + srow + 16) * K + scol;
  const u16* bgp0 = Bt + (size_t)(bcol + srow) * K + scol;
  const u16* bgp1 = Bt + (size_t)(bcol + srow + 16) * K + scol;
  u16* al0 = &As[wave * 1024];       u16* al1 = &As[wave * 1024 + 512];
  u16* bl0 = &Bs[wave * 1024];       u16* bl1 = &Bs[wave * 1024 + 512];
  for (int k0 = 0; k0 < K; k0 += 32) {
    __syncthreads();
    gld16(agp0 + k0, al0);
    gld16(agp1 + k0, al1);
    gld16(bgp0 + k0, bl0);
    gld16(bgp1 + k0, bl1);
    __syncthreads();
    bf16x8 af[4], bfr[4];
    #pragma unroll
    for (int mi = 0; mi < 4; ++mi)
      af[mi] = *reinterpret_cast<const bf16x8*>(&As[(wr + mi * 16 + c) * 32 + g * 8]);
    #pragma unroll
    for (int ni = 0; ni < 4; ++ni)
      bfr[ni] = *reinterpret_cast<const bf16x8*>(&Bs[(wc + ni * 16 + c) * 32 + g * 8]);
    #pragma unroll
    for (int mi = 0; mi < 4; ++mi)
      #pragma unroll
      for (int ni = 0; ni < 4; ++ni)
        acc[mi][ni] = MFMA16(af[mi], bfr[ni], acc[mi][ni]);
  }
  #pragma unroll
  for (int mi = 0; mi < 4; ++mi) {
    #pragma unroll
    for (int ni = 0; ni < 4; ++ni) {
      const int col = bcol + wc + ni * 16 + c;
      const float bz = bias[col];
      #pragma unroll
      for (int i = 0; i < 4; ++i) {
        const int row = brow + wr + mi * 16 + g * 4 + i;
        float v = acc[mi][ni][i] + bz;
        if (EPI == 0) {
          if (col < 768)       oq[(size_t)row * 768 + col]        = f2bf(v);
          else if (col < 1536) ok[(size_t)row * 768 + col - 768]  = f2bf(v);
          else                 ov[(size_t)row * 768 + col - 1536] = f2bf(v);
        } else {
          of[(size_t)row * 768 + col] = v;
        }
      }
    }
  }
}

// ---------------- 2x2 max-pool on q (bf16) + fold scale*log2e ----------------
__global__ void qpool(const u16* __restrict__ qf, u16* __restrict__ qp) {
  int idx = blockIdx.x * blockDim.x + threadIdx.x;
  if (idx >= 4096 * 96) return;
  const float SC = 0.14724744f;  // 96^-0.5 * log2(e)
  int r = idx / 96, cc = (idx - r * 96) * 8;
  int b = r >> 10, ij = r & 1023, ii = ij >> 5, jj = ij & 31;
  const size_t base = ((size_t)b * 4096 + (size_t)ii * 128 + jj * 2) * 768 + cc;
  u16x8 x0 = *reinterpret_cast<const u16x8*>(qf + base);
  u16x8 x1 = *reinterpret_cast<const u16x8*>(qf + base + 768);
  u16x8 x2 = *reinterpret_cast<const u16x8*>(qf + base + 64 * 768);
  u16x8 x3 = *reinterpret_cast<const u16x8*>(qf + base + 65 * 768);
  u16x8 o;
  #pragma unroll
  for (int e = 0; e < 8; ++e) {
    float mv = bf2f(x0[e]);
    mv = fmaxf(mv, bf2f(x1[e]));
    mv = fmaxf(mv, bf2f(x2[e]));
    mv = fmaxf(mv, bf2f(x3[e]));
    o[e] = f2bf(mv * SC);
  }
  *reinterpret_cast<u16x8*>(qp + (size_t)r * 768 + cc) = o;
}

// ---------------- V transpose: vbuf[16384][768] -> vT[(bh*96+d)*4096 + sp] ----------------
__global__ void vtrans(const u16* __restrict__ vbuf, u16* __restrict__ vT) {
  __shared__ u16 T[64][97];
  const int blk = blockIdx.x;           // (bh)*64 + tile
  const int st = blk & 63, bh = blk >> 6;
  const int b = bh >> 3, h = bh & 7;
  const int tid = threadIdx.x;
  const u16* src = vbuf + ((size_t)(b * 4096 + st * 64)) * 768 + h * 96;
  #pragma unroll
  for (int j = 0; j < 3; ++j) {
    int p = tid + 256 * j;              // 0..767
    int r = p / 12, ch = p - r * 12;
    u16x8 v = *reinterpret_cast<const u16x8*>(src + (size_t)r * 768 + ch * 8);
    #pragma unroll
    for (int e = 0; e < 8; ++e) T[r][ch * 8 + e] = v[e];
  }
  __syncthreads();
  u16* dst = vT + ((size_t)(bh * 96)) * 4096 + st * 64;
  #pragma unroll
  for (int j = 0; j < 3; ++j) {
    int oc = tid + 256 * j;             // 0..767
    int d = oc >> 3, part = oc & 7;
    u16x8 o;
    #pragma unroll
    for (int e = 0; e < 8; ++e) o[e] = T[part * 8 + e][d];
    *reinterpret_cast<u16x8*>(dst + (size_t)d * 4096 + part * 8) = o;
  }
}

// ---------------- flash attention, KVBLK=64, key-split x2, partial out ----------------
// grid 1024: blk = ((bh*16 + qt) * 2 + sp). 4 waves; wave w owns q rows qt*64+w*16..+15.
__launch_bounds__(256)
__global__ void flash2(const u16* __restrict__ Qp, const u16* __restrict__ Kb,
                       const u16* __restrict__ Vtg,
                       float* __restrict__ pacc, float* __restrict__ pml) {
  const int blk = blockIdx.x;
  const int sp = blk & 1, qt = (blk >> 1) & 15, bh = blk >> 5;
  const int b = bh >> 3, h = bh & 7;
  __shared__ __align__(16) u16 Ks[64 * 96];      // natural [key][96]
  __shared__ __align__(16) u16 Vs[96 * 64];      // [d][64 keys], chunk-swizzled by d&7
  __shared__ __align__(16) u16 Pl[4 * 16 * 64];  // per-wave [16 q][64 keys], swizzled
  const int tid = threadIdx.x, w = tid >> 6, lane = tid & 63;
  const int c = lane & 15, g = lane >> 4;
  // Q fragments (pre-scaled by scale*log2e)
  const u16* qb = Qp + ((size_t)(b * 1024 + qt * 64 + w * 16 + c)) * 768 + h * 96;
  bf16x8 qf[3];
  #pragma unroll
  for (int kc = 0; kc < 3; ++kc)
    qf[kc] = *reinterpret_cast<const bf16x8*>(qb + kc * 32 + g * 8);
  // staging thread-constants
  int koff[3], voff[3];
  #pragma unroll
  for (int j = 0; j < 3; ++j) {
    int p = w * 192 + j * 64 + lane;    // 0..767
    int r = p / 12, ch = p - r * 12;    // K: row r, chunk ch (12 x 16B per row)
    koff[j] = r * 768 + ch * 8;
    int d = p >> 3, vch = p & 7;        // V: row d (8 x 16B per row), pre-swizzled src
    voff[j] = d * 4096 + ((vch ^ (d & 7)) * 8);
  }
  u16* kl[3]; u16* vl[3];
  #pragma unroll
  for (int j = 0; j < 3; ++j) {
    kl[j] = &Ks[(w * 192 + j * 64) * 8];
    vl[j] = &Vs[(w * 192 + j * 64) * 8];
  }
  const u16* kb0 = Kb + ((size_t)(b * 4096 + sp * 2048)) * 768 + h * 96;
  const u16* vb0 = Vtg + ((size_t)(bh * 96)) * 4096 + sp * 2048;
  float m[4], l[4];
  f32x4 acc[6] = {};
  #pragma unroll
  for (int i = 0; i < 4; ++i) { m[i] = -1e30f; l[i] = 0.f; }
  const int sw = (c & 7) << 3;          // read-side chunk swizzle (u16 index)
  for (int kt = 0; kt < 32; ++kt) {
    __syncthreads();
    #pragma unroll
    for (int j = 0; j < 3; ++j) gld16(kb0 + (size_t)kt * 49152 + koff[j], kl[j]);
    #pragma unroll
    for (int j = 0; j < 3; ++j) gld16(vb0 + kt * 64 + voff[j], vl[j]);
    __syncthreads();
    // QK^T: S[q=g*4+i][key = kt4*16+c]
    f32x4 st[4] = {};
    #pragma unroll
    for (int kc = 0; kc < 3; ++kc)
      #pragma unroll
      for (int kt4 = 0; kt4 < 4; ++kt4) {
        bf16x8 kf = *reinterpret_cast<const bf16x8*>(&Ks[(kt4 * 16 + c) * 96 + kc * 32 + g * 8]);
        st[kt4] = MFMA16(qf[kc], kf, st[kt4]);
      }
    // online softmax (base-2 domain)
    float esc[4];
    #pragma unroll
    for (int i = 0; i < 4; ++i) {
      float r0 = fmaxf(fmaxf(st[0][i], st[1][i]), fmaxf(st[2][i], st[3][i]));
      r0 = fmaxf(r0, __shfl_xor(r0, 1));
      r0 = fmaxf(r0, __shfl_xor(r0, 2));
      r0 = fmaxf(r0, __shfl_xor(r0, 4));
      r0 = fmaxf(r0, __shfl_xor(r0, 8));
      float mn = fmaxf(m[i], r0);
      esc[i] = exp2f(m[i] - mn);
      float p0 = exp2f(st[0][i] - mn);
      float p1 = exp2f(st[1][i] - mn);
      float p2 = exp2f(st[2][i] - mn);
      float p3 = exp2f(st[3][i] - mn);
      st[0][i] = p0; st[1][i] = p1; st[2][i] = p2; st[3][i] = p3;
      float rs = (p0 + p1) + (p2 + p3);
      rs += __shfl_xor(rs, 1);
      rs += __shfl_xor(rs, 2);
      rs += __shfl_xor(rs, 4);
      rs += __shfl_xor(rs, 8);
      l[i] = l[i] * esc[i] + rs;
      m[i] = mn;
    }
    #pragma unroll
    for (int dc = 0; dc < 6; ++dc)
      #pragma unroll
      for (int i = 0; i < 4; ++i)
        acc[dc][i] *= esc[i];
    // write P (bf16) into per-wave swizzled LDS
    #pragma unroll
    for (int i = 0; i < 4; ++i) {
      const int row = g * 4 + i, rs8 = (row & 7) << 3;
      #pragma unroll
      for (int kt4 = 0; kt4 < 4; ++kt4)
        Pl[w * 1024 + row * 64 + ((kt4 * 16 + c) ^ rs8)] = f2bf(st[kt4][i]);
    }
    asm volatile("s_waitcnt lgkmcnt(0)" ::: "memory");  // per-wave P write->read ordering
    // PV: acc[dc] += P * V
    #pragma unroll
    for (int kh = 0; kh < 2; ++kh) {
      bf16x8 pf = *reinterpret_cast<const bf16x8*>(&Pl[w * 1024 + c * 64 + ((kh * 32 + g * 8) ^ sw)]);
      #pragma unroll
      for (int dc = 0; dc < 6; ++dc) {
        bf16x8 vf = *reinterpret_cast<const bf16x8*>(&Vs[(dc * 16 + c) * 64 + ((kh * 32 + g * 8) ^ sw)]);
        acc[dc] = MFMA16(pf, vf, acc[dc]);
      }
    }
  }
  // write partial (unnormalized acc, m, l)
  const int prow = blk * 64 + w * 16;
  #pragma unroll
  for (int dc = 0; dc < 6; ++dc)
    #pragma unroll
    for (int i = 0; i < 4; ++i)
      pacc[(size_t)(prow + g * 4 + i) * 96 + dc * 16 + c] = acc[dc][i];
  if (c < 2) {
    #pragma unroll
    for (int i = 0; i < 4; ++i)
      pml[(prow + g * 4 + i) * 2 + c] = (c == 0) ? m[i] : l[i];
  }
}

// ---------------- combine 2 key-splits -> aout (bf16) ----------------
__global__ void fcomb(const float* __restrict__ pacc, const float* __restrict__ pml,
                      u16* __restrict__ aout) {
  const int bhqt = blockIdx.x;          // 512
  const int qt = bhqt & 15, bh = bhqt >> 4;
  const int b = bh >> 3, h = bh & 7;
  const int p0 = bhqt * 2, p1 = p0 + 1;
  const int tid = threadIdx.x;
  #pragma unroll
  for (int j = 0; j < 6; ++j) {
    int idx = tid + 256 * j;            // 0..1535 f32x4 chunks
    int r = idx / 24, dq = idx - r * 24;
    float m0 = pml[(p0 * 64 + r) * 2], l0 = pml[(p0 * 64 + r) * 2 + 1];
    float m1 = pml[(p1 * 64 + r) * 2], l1 = pml[(p1 * 64 + r) * 2 + 1];
    float M = fmaxf(m0, m1);
    float e0 = exp2f(m0 - M), e1 = exp2f(m1 - M);
    float inv = 1.f / (l0 * e0 + l1 * e1);
    f32x4 a0 = *reinterpret_cast<const f32x4*>(pacc + ((size_t)(p0 * 64 + r)) * 96 + dq * 4);
    f32x4 a1 = *reinterpret_cast<const f32x4*>(pacc + ((size_t)(p1 * 64 + r)) * 96 + dq * 4);
    ushort4 o;
    o.x = f2bf((a0[0] * e0 + a1[0] * e1) * inv);
    o.y = f2bf((a0[1] * e0 + a1[1] * e1) * inv);
    o.z = f2bf((a0[2] * e0 + a1[2] * e1) * inv);
    o.w = f2bf((a0[3] * e0 + a1[3] * e1) * inv);
    *reinterpret_cast<ushort4*>(aout + (size_t)(b * 1024 + qt * 64 + r) * 768 + h * 96 + dq * 4) = o;
  }
}

extern "C" void kernel_launch(void* const* d_in, const int* in_sizes, int n_in,
                              void* d_out, int out_size, void* d_ws, size_t ws_size,
                              hipStream_t stream) {
  const float* hs     = (const float*)d_in[0];
  const float* qkv_w  = (const float*)d_in[1];
  const float* qkv_b  = (const float*)d_in[2];
  const float* proj_w = (const float*)d_in[3];
  const float* proj_b = (const float*)d_in[4];
  float* out = (float*)d_out;

  u16* hs_bf  = (u16*)d_ws;                 // 6291456 u16 (dead after gemm<0>) -> pml
  u16* qkvwT  = hs_bf  + 6291456;           // 884736
  u16* projwT = qkvwT  + 884736;            // 589824
  u16* qfull  = projwT + 589824;            // 12582912 (dead after qpool) -> vT
  u16* kbuf   = qfull  + 12582912;          // 12582912
  u16* vbuf   = kbuf   + 12582912;          // 12582912 (dead after vtrans) -> pacc
  u16* qpol   = vbuf   + 12582912;          // 3145728
  u16* aout   = qpol   + 3145728;           // 3145728

  u16* vT     = qfull;                      // 32*96*4096 = 12582912 u16, exact fit
  float* pacc = (float*)vbuf;               // 1024*64*96*4B = 25165824 B, exact fit
  float* pml  = (float*)hs_bf;              // 524288 B

  cast4<<<6144, 256, 0, stream>>>(hs, hs_bf, 1572864);
  tcast<<<3456, 256, 0, stream>>>(qkv_w, qkvwT, 384, 2304);
  tcast<<<2304, 256, 0, stream>>>(proj_w, projwT, 768, 768);

  gemm_bt<0><<<dim3(18, 128), 256, 0, stream>>>(hs_bf, qkvwT, qkv_b,
                                                qfull, kbuf, vbuf, nullptr, 384);
  qpool<<<1536, 256, 0, stream>>>(qfull, qpol);
  vtrans<<<2048, 256, 0, stream>>>(vbuf, vT);
  flash2<<<1024, 256, 0, stream>>>(qpol, kbuf, vT, pacc, pml);
  fcomb<<<512, 256, 0, stream>>>(pacc, pml, aout);
  gemm_bt<1><<<dim3(6, 32), 256, 0, stream>>>(aout, projwT, proj_b,
                                              nullptr, nullptr, nullptr, out, 768);
}

// Round 4
// 237.885 us; speedup vs baseline: 3.3607x; 1.2031x over previous
//
#include <hip/hip_runtime.h>
#include <hip/hip_bf16.h>

typedef unsigned short u16;
typedef __attribute__((ext_vector_type(8))) short bf16x8;
typedef __attribute__((ext_vector_type(8))) unsigned short u16x8;
typedef __attribute__((ext_vector_type(4))) float f32x4;

#define MFMA16(a,b,c) __builtin_amdgcn_mfma_f32_16x16x32_bf16(a,b,c,0,0,0)

__device__ __forceinline__ u16 f2bf(float f) {
  union { float f; unsigned int u; } v; v.f = f;
  unsigned int r = v.u + 0x7fffu + ((v.u >> 16) & 1u);  // RNE, finite inputs
  return (u16)(r >> 16);
}
__device__ __forceinline__ float bf2f(u16 u) {
  union { unsigned int i; float f; } v; v.i = ((unsigned int)u) << 16; return v.f;
}

__device__ __forceinline__ void gld16(const void* g, void* l) {
  __builtin_amdgcn_global_load_lds((const __attribute__((address_space(1))) void*)g,
                                   (__attribute__((address_space(3))) void*)l, 16, 0, 0);
}

// ---------------- cast fp32 -> bf16 (4/thread) ----------------
__global__ void cast4(const float* __restrict__ in, u16* __restrict__ out, int n4) {
  int i = blockIdx.x * blockDim.x + threadIdx.x;
  if (i >= n4) return;
  float4 v = reinterpret_cast<const float4*>(in)[i];
  ushort4 o; o.x = f2bf(v.x); o.y = f2bf(v.y); o.z = f2bf(v.z); o.w = f2bf(v.w);
  reinterpret_cast<ushort4*>(out)[i] = o;
}

// ---------------- transpose-cast weight: out[n*K+k] = bf16(in[k*N+n]) ----------------
__global__ void tcast(const float* __restrict__ in, u16* __restrict__ out, int K, int N) {
  int idx = blockIdx.x * blockDim.x + threadIdx.x;
  if (idx >= K * N) return;
  int n = idx / K, k = idx - n * K;
  out[idx] = f2bf(in[(size_t)k * N + n]);
}

// ---------------- GEMM: C[M,N] = A[M,K] * Bt[N,K]^T + bias ----------------
template<int EPI>
__launch_bounds__(256)
__global__ void gemm_bt(const u16* __restrict__ A, const u16* __restrict__ Bt,
                        const float* __restrict__ bias,
                        u16* __restrict__ oq, u16* __restrict__ ok, u16* __restrict__ ov,
                        float* __restrict__ of, int K) {
  __shared__ __align__(16) u16 As[128 * 32];
  __shared__ __align__(16) u16 Bs[128 * 32];
  const int tid = threadIdx.x;
  const int wave = tid >> 6, lane = tid & 63;
  const int c = lane & 15, g = lane >> 4;
  const int brow = blockIdx.y * 128, bcol = blockIdx.x * 128;
  const int wr = (wave >> 1) * 64, wc = (wave & 1) * 64;
  f32x4 acc[4][4] = {};
  const int srow = wave * 32 + (lane >> 2);
  const int scol = (lane & 3) * 8;
  const u16* agp0 = A  + (size_t)(brow + srow) * K + scol;
  const u16* agp1 = A  + (size_t)(brow + srow + 16) * K + scol;
  const u16* bgp0 = Bt + (size_t)(bcol + srow) * K + scol;
  const u16* bgp1 = Bt + (size_t)(bcol + srow + 16) * K + scol;
  u16* al0 = &As[wave * 1024];       u16* al1 = &As[wave * 1024 + 512];
  u16* bl0 = &Bs[wave * 1024];       u16* bl1 = &Bs[wave * 1024 + 512];
  for (int k0 = 0; k0 < K; k0 += 32) {
    __syncthreads();
    gld16(agp0 + k0, al0);
    gld16(agp1 + k0, al1);
    gld16(bgp0 + k0, bl0);
    gld16(bgp1 + k0, bl1);
    __syncthreads();
    bf16x8 af[4], bfr[4];
    #pragma unroll
    for (int mi = 0; mi < 4; ++mi)
      af[mi] = *reinterpret_cast<const bf16x8*>(&As[(wr + mi * 16 + c) * 32 + g * 8]);
    #pragma unroll
    for (int ni = 0; ni < 4; ++ni)
      bfr[ni] = *reinterpret_cast<const bf16x8*>(&Bs[(wc + ni * 16 + c) * 32 + g * 8]);
    #pragma unroll
    for (int mi = 0; mi < 4; ++mi)
      #pragma unroll
      for (int ni = 0; ni < 4; ++ni)
        acc[mi][ni] = MFMA16(af[mi], bfr[ni], acc[mi][ni]);
  }
  #pragma unroll
  for (int mi = 0; mi < 4; ++mi) {
    #pragma unroll
    for (int ni = 0; ni < 4; ++ni) {
      const int col = bcol + wc + ni * 16 + c;
      const float bz = bias[col];
      #pragma unroll
      for (int i = 0; i < 4; ++i) {
        const int row = brow + wr + mi * 16 + g * 4 + i;
        float v = acc[mi][ni][i] + bz;
        if (EPI == 0) {
          if (col < 768)       oq[(size_t)row * 768 + col]        = f2bf(v);
          else if (col < 1536) ok[(size_t)row * 768 + col - 768]  = f2bf(v);
          else                 ov[(size_t)row * 768 + col - 1536] = f2bf(v);
        } else {
          of[(size_t)row * 768 + col] = v;
        }
      }
    }
  }
}

// ---------------- 2x2 max-pool on q (bf16) + fold scale*log2e ----------------
__global__ void qpool(const u16* __restrict__ qf, u16* __restrict__ qp) {
  int idx = blockIdx.x * blockDim.x + threadIdx.x;
  if (idx >= 4096 * 96) return;
  const float SC = 0.14724744f;  // 96^-0.5 * log2(e)
  int r = idx / 96, cc = (idx - r * 96) * 8;
  int b = r >> 10, ij = r & 1023, ii = ij >> 5, jj = ij & 31;
  const size_t base = ((size_t)b * 4096 + (size_t)ii * 128 + jj * 2) * 768 + cc;
  u16x8 x0 = *reinterpret_cast<const u16x8*>(qf + base);
  u16x8 x1 = *reinterpret_cast<const u16x8*>(qf + base + 768);
  u16x8 x2 = *reinterpret_cast<const u16x8*>(qf + base + 64 * 768);
  u16x8 x3 = *reinterpret_cast<const u16x8*>(qf + base + 65 * 768);
  u16x8 o;
  #pragma unroll
  for (int e = 0; e < 8; ++e) {
    float mv = bf2f(x0[e]);
    mv = fmaxf(mv, bf2f(x1[e]));
    mv = fmaxf(mv, bf2f(x2[e]));
    mv = fmaxf(mv, bf2f(x3[e]));
    o[e] = f2bf(mv * SC);
  }
  *reinterpret_cast<u16x8*>(qp + (size_t)r * 768 + cc) = o;
}

// ---------------- V transpose: vbuf[16384][768] -> vT[(bh*96+d)*4096 + sp] ----------------
__global__ void vtrans(const u16* __restrict__ vbuf, u16* __restrict__ vT) {
  __shared__ u16 T[64][97];
  const int blk = blockIdx.x;           // (bh)*64 + tile
  const int st = blk & 63, bh = blk >> 6;
  const int b = bh >> 3, h = bh & 7;
  const int tid = threadIdx.x;
  const u16* src = vbuf + ((size_t)(b * 4096 + st * 64)) * 768 + h * 96;
  #pragma unroll
  for (int j = 0; j < 3; ++j) {
    int p = tid + 256 * j;              // 0..767
    int r = p / 12, ch = p - r * 12;
    u16x8 v = *reinterpret_cast<const u16x8*>(src + (size_t)r * 768 + ch * 8);
    #pragma unroll
    for (int e = 0; e < 8; ++e) T[r][ch * 8 + e] = v[e];
  }
  __syncthreads();
  u16* dst = vT + ((size_t)(bh * 96)) * 4096 + st * 64;
  #pragma unroll
  for (int j = 0; j < 3; ++j) {
    int oc = tid + 256 * j;             // 0..767
    int d = oc >> 3, part = oc & 7;
    u16x8 o;
    #pragma unroll
    for (int e = 0; e < 8; ++e) o[e] = T[part * 8 + e][d];
    *reinterpret_cast<u16x8*>(dst + (size_t)d * 4096 + part * 8) = o;
  }
}

// ---------------- flash attention, swapped-QK^T softmax, KVBLK=64, key-split x2 ----------------
// grid 1024: blk = ((bh*16 + qt) * 2 + sp). 4 waves; wave w owns q rows qt*64+w*16..+15.
__launch_bounds__(256)
__global__ void flash3(const u16* __restrict__ Qp, const u16* __restrict__ Kb,
                       const u16* __restrict__ Vtg,
                       float* __restrict__ pacc, float* __restrict__ pml) {
  const int blk = blockIdx.x;
  const int sp = blk & 1, qt = (blk >> 1) & 15, bh = blk >> 5;
  const int b = bh >> 3, h = bh & 7;
  __shared__ __align__(16) u16 Ks[64 * 96];      // natural [key][96]
  __shared__ __align__(16) u16 Vs[96 * 64];      // [d][64 keys], chunk-swizzled by d&7
  __shared__ __align__(16) u16 Pl[4 * 16 * 64];  // per-wave [16 q][64 keys], 8B-chunk swz
  const int tid = threadIdx.x, w = tid >> 6, lane = tid & 63;
  const int c = lane & 15, g = lane >> 4;
  // Q fragments (pre-scaled by scale*log2e); q = c
  const u16* qb = Qp + ((size_t)(b * 1024 + qt * 64 + w * 16 + c)) * 768 + h * 96;
  bf16x8 qf[3];
  #pragma unroll
  for (int kc = 0; kc < 3; ++kc)
    qf[kc] = *reinterpret_cast<const bf16x8*>(qb + kc * 32 + g * 8);
  // staging thread-constants
  int koff[3], voff[3];
  #pragma unroll
  for (int j = 0; j < 3; ++j) {
    int p = w * 192 + j * 64 + lane;    // 0..767
    int r = p / 12, ch = p - r * 12;    // K: row r, chunk ch (12 x 16B per row)
    koff[j] = r * 768 + ch * 8;
    int d = p >> 3, vch = p & 7;        // V: row d (8 x 16B per row), pre-swizzled src
    voff[j] = d * 4096 + ((vch ^ (d & 7)) * 8);
  }
  u16* kl[3]; u16* vl[3];
  #pragma unroll
  for (int j = 0; j < 3; ++j) {
    kl[j] = &Ks[(w * 192 + j * 64) * 8];
    vl[j] = &Vs[(w * 192 + j * 64) * 8];
  }
  const u16* kb0 = Kb + ((size_t)(b * 4096 + sp * 2048)) * 768 + h * 96;
  const u16* vb0 = Vtg + ((size_t)(bh * 96)) * 4096 + sp * 2048;
  float m = -1e30f, l = 0.f;            // per-lane, q = c domain (replicated over g)
  f32x4 acc[6] = {};
  const int sw = (c & 7) << 3;          // Vs read-side chunk swizzle (u16 index)
  const int psw = (c & 7) << 1;         // Pl 8B-chunk swizzle (even -> keeps pairs)
  const int pbase = w * 1024 + c * 64;
  for (int kt = 0; kt < 32; ++kt) {
    __syncthreads();
    #pragma unroll
    for (int j = 0; j < 3; ++j) gld16(kb0 + (size_t)kt * 49152 + koff[j], kl[j]);
    #pragma unroll
    for (int j = 0; j < 3; ++j) gld16(vb0 + kt * 64 + voff[j], vl[j]);
    __syncthreads();
    // swapped QK^T: st[kt4] = S^T[key = kt4*16 + g*4 + i][q = c]
    f32x4 st[4] = {};
    #pragma unroll
    for (int kc = 0; kc < 3; ++kc)
      #pragma unroll
      for (int kt4 = 0; kt4 < 4; ++kt4) {
        bf16x8 kf = *reinterpret_cast<const bf16x8*>(&Ks[(kt4 * 16 + c) * 96 + kc * 32 + g * 8]);
        st[kt4] = MFMA16(kf, qf[kc], st[kt4]);
      }
    // per-lane max over 16 in-register keys, then cross-g (2 shfl)
    float pmax = st[0][0];
    #pragma unroll
    for (int kt4 = 0; kt4 < 4; ++kt4)
      #pragma unroll
      for (int i = 0; i < 4; ++i)
        pmax = fmaxf(pmax, st[kt4][i]);
    pmax = fmaxf(pmax, __shfl_xor(pmax, 16));
    pmax = fmaxf(pmax, __shfl_xor(pmax, 32));
    // defer-max: rescale only when max grew past threshold (wave-uniform branch)
    if (__any(pmax > m + 8.0f)) {
      float mn = fmaxf(m, pmax);
      float esc = exp2f(m - mn);
      m = mn;
      l *= esc;
      float er[4];
      #pragma unroll
      for (int i = 0; i < 4; ++i) er[i] = __shfl(esc, g * 4 + i);  // esc for acc row q=g*4+i
      #pragma unroll
      for (int dc = 0; dc < 6; ++dc)
        #pragma unroll
        for (int i = 0; i < 4; ++i)
          acc[dc][i] *= er[i];
    }
    // P = exp2(S - m), row-sum (in-lane + 2 shfl)
    float ps = 0.f;
    #pragma unroll
    for (int kt4 = 0; kt4 < 4; ++kt4)
      #pragma unroll
      for (int i = 0; i < 4; ++i) {
        float p = exp2f(st[kt4][i] - m);
        st[kt4][i] = p;
        ps += p;
      }
    ps += __shfl_xor(ps, 16);
    ps += __shfl_xor(ps, 32);
    l += ps;
    // pack P -> bf16 pairs, write 4 keys (8B) per kt4 into swizzled Pl row q=c
    #pragma unroll
    for (int kt4 = 0; kt4 < 4; ++kt4) {
      unsigned int u0, u1;
      asm("v_cvt_pk_bf16_f32 %0, %1, %2" : "=v"(u0) : "v"(st[kt4][0]), "v"(st[kt4][1]));
      asm("v_cvt_pk_bf16_f32 %0, %1, %2" : "=v"(u1) : "v"(st[kt4][2]), "v"(st[kt4][3]));
      const int chunk = (kt4 * 4 + g) ^ psw;
      *reinterpret_cast<uint2*>(&Pl[pbase + chunk * 4]) = make_uint2(u0, u1);
    }
    asm volatile("s_waitcnt lgkmcnt(0)" ::: "memory");  // per-wave P write->read ordering
    // PV: acc[dc] += P * V   (acc row = q = g*4+i, col d = dc*16+c)
    #pragma unroll
    for (int kh = 0; kh < 2; ++kh) {
      const int rchunk = (kh * 8 + g * 2) ^ psw;
      bf16x8 pf = *reinterpret_cast<const bf16x8*>(&Pl[pbase + rchunk * 4]);
      #pragma unroll
      for (int dc = 0; dc < 6; ++dc) {
        bf16x8 vf = *reinterpret_cast<const bf16x8*>(&Vs[(dc * 16 + c) * 64 + ((kh * 32 + g * 8) ^ sw)]);
        acc[dc] = MFMA16(pf, vf, acc[dc]);
      }
    }
  }
  // write partial (unnormalized acc, m, l)
  const int prow = blk * 64 + w * 16;
  #pragma unroll
  for (int dc = 0; dc < 6; ++dc)
    #pragma unroll
    for (int i = 0; i < 4; ++i)
      pacc[(size_t)(prow + g * 4 + i) * 96 + dc * 16 + c] = acc[dc][i];
  if (lane < 16) {
    pml[(prow + lane) * 2]     = m;
    pml[(prow + lane) * 2 + 1] = l;
  }
}

// ---------------- combine 2 key-splits -> aout (bf16) ----------------
__global__ void fcomb(const float* __restrict__ pacc, const float* __restrict__ pml,
                      u16* __restrict__ aout) {
  const int bhqt = blockIdx.x;          // 512
  const int qt = bhqt & 15, bh = bhqt >> 4;
  const int b = bh >> 3, h = bh & 7;
  const int p0 = bhqt * 2, p1 = p0 + 1;
  const int tid = threadIdx.x;
  #pragma unroll
  for (int j = 0; j < 6; ++j) {
    int idx = tid + 256 * j;            // 0..1535 f32x4 chunks
    int r = idx / 24, dq = idx - r * 24;
    float m0 = pml[(p0 * 64 + r) * 2], l0 = pml[(p0 * 64 + r) * 2 + 1];
    float m1 = pml[(p1 * 64 + r) * 2], l1 = pml[(p1 * 64 + r) * 2 + 1];
    float M = fmaxf(m0, m1);
    float e0 = exp2f(m0 - M), e1 = exp2f(m1 - M);
    float inv = 1.f / (l0 * e0 + l1 * e1);
    f32x4 a0 = *reinterpret_cast<const f32x4*>(pacc + ((size_t)(p0 * 64 + r)) * 96 + dq * 4);
    f32x4 a1 = *reinterpret_cast<const f32x4*>(pacc + ((size_t)(p1 * 64 + r)) * 96 + dq * 4);
    ushort4 o;
    o.x = f2bf((a0[0] * e0 + a1[0] * e1) * inv);
    o.y = f2bf((a0[1] * e0 + a1[1] * e1) * inv);
    o.z = f2bf((a0[2] * e0 + a1[2] * e1) * inv);
    o.w = f2bf((a0[3] * e0 + a1[3] * e1) * inv);
    *reinterpret_cast<ushort4*>(aout + (size_t)(b * 1024 + qt * 64 + r) * 768 + h * 96 + dq * 4) = o;
  }
}

extern "C" void kernel_launch(void* const* d_in, const int* in_sizes, int n_in,
                              void* d_out, int out_size, void* d_ws, size_t ws_size,
                              hipStream_t stream) {
  const float* hs     = (const float*)d_in[0];
  const float* qkv_w  = (const float*)d_in[1];
  const float* qkv_b  = (const float*)d_in[2];
  const float* proj_w = (const float*)d_in[3];
  const float* proj_b = (const float*)d_in[4];
  float* out = (float*)d_out;

  u16* hs_bf  = (u16*)d_ws;                 // 6291456 u16 (dead after gemm<0>) -> pml
  u16* qkvwT  = hs_bf  + 6291456;           // 884736
  u16* projwT = qkvwT  + 884736;            // 589824
  u16* qfull  = projwT + 589824;            // 12582912 (dead after qpool) -> vT
  u16* kbuf   = qfull  + 12582912;          // 12582912
  u16* vbuf   = kbuf   + 12582912;          // 12582912 (dead after vtrans) -> pacc
  u16* qpol   = vbuf   + 12582912;          // 3145728
  u16* aout   = qpol   + 3145728;           // 3145728

  u16* vT     = qfull;                      // 32*96*4096 = 12582912 u16, exact fit
  float* pacc = (float*)vbuf;               // 1024*64*96*4B = 25165824 B, exact fit
  float* pml  = (float*)hs_bf;              // 524288 B

  cast4<<<6144, 256, 0, stream>>>(hs, hs_bf, 1572864);
  tcast<<<3456, 256, 0, stream>>>(qkv_w, qkvwT, 384, 2304);
  tcast<<<2304, 256, 0, stream>>>(proj_w, projwT, 768, 768);

  gemm_bt<0><<<dim3(18, 128), 256, 0, stream>>>(hs_bf, qkvwT, qkv_b,
                                                qfull, kbuf, vbuf, nullptr, 384);
  qpool<<<1536, 256, 0, stream>>>(qfull, qpol);
  vtrans<<<2048, 256, 0, stream>>>(vbuf, vT);
  flash3<<<1024, 256, 0, stream>>>(qpol, kbuf, vT, pacc, pml);
  fcomb<<<512, 256, 0, stream>>>(pacc, pml, aout);
  gemm_bt<1><<<dim3(6, 32), 256, 0, stream>>>(aout, projwT, proj_b,
                                              nullptr, nullptr, nullptr, out, 768);
}

// Round 5
// 236.077 us; speedup vs baseline: 3.3864x; 1.0077x over previous
//
#include <hip/hip_runtime.h>
#include <hip/hip_bf16.h>

typedef unsigned short u16;
typedef __attribute__((ext_vector_type(8))) short bf16x8;
typedef __attribute__((ext_vector_type(8))) unsigned short u16x8;
typedef __attribute__((ext_vector_type(4))) float f32x4;

#define MFMA16(a,b,c) __builtin_amdgcn_mfma_f32_16x16x32_bf16(a,b,c,0,0,0)

__device__ __forceinline__ u16 f2bf(float f) {
  union { float f; unsigned int u; } v; v.f = f;
  unsigned int r = v.u + 0x7fffu + ((v.u >> 16) & 1u);  // RNE, finite inputs
  return (u16)(r >> 16);
}
__device__ __forceinline__ float bf2f(u16 u) {
  union { unsigned int i; float f; } v; v.i = ((unsigned int)u) << 16; return v.f;
}

__device__ __forceinline__ void gld16(const void* g, void* l) {
  __builtin_amdgcn_global_load_lds((const __attribute__((address_space(1))) void*)g,
                                   (__attribute__((address_space(3))) void*)l, 16, 0, 0);
}

// ---------------- cast fp32 -> bf16 (4/thread) ----------------
__global__ void cast4(const float* __restrict__ in, u16* __restrict__ out, int n4) {
  int i = blockIdx.x * blockDim.x + threadIdx.x;
  if (i >= n4) return;
  float4 v = reinterpret_cast<const float4*>(in)[i];
  ushort4 o; o.x = f2bf(v.x); o.y = f2bf(v.y); o.z = f2bf(v.z); o.w = f2bf(v.w);
  reinterpret_cast<ushort4*>(out)[i] = o;
}

// ---------------- transpose-cast weight: out[n*K+k] = bf16(in[k*N+n]) ----------------
__global__ void tcast(const float* __restrict__ in, u16* __restrict__ out, int K, int N) {
  int idx = blockIdx.x * blockDim.x + threadIdx.x;
  if (idx >= K * N) return;
  int n = idx / K, k = idx - n * K;
  out[idx] = f2bf(in[(size_t)k * N + n]);
}

// ---------------- GEMM: C[M,N] = A[M,K] * Bt[N,K]^T + bias ----------------
// 128x128 tile, BK=32, double-buffered LDS, counted-vmcnt prefetch pipeline.
template<int EPI>
__launch_bounds__(256)
__global__ void gemm_bt(const u16* __restrict__ A, const u16* __restrict__ Bt,
                        const float* __restrict__ bias,
                        u16* __restrict__ oq, u16* __restrict__ ok, u16* __restrict__ ov,
                        float* __restrict__ of, int K) {
  __shared__ __align__(16) u16 As[2][128 * 32];
  __shared__ __align__(16) u16 Bs[2][128 * 32];
  const int tid = threadIdx.x;
  const int wave = tid >> 6, lane = tid & 63;
  const int c = lane & 15, g = lane >> 4;
  const int brow = blockIdx.y * 128, bcol = blockIdx.x * 128;
  const int wr = (wave >> 1) * 64, wc = (wave & 1) * 64;
  f32x4 acc[4][4] = {};
  const int srow = wave * 32 + (lane >> 2);
  const int scol = (lane & 3) * 8;
  const u16* agp0 = A  + (size_t)(brow + srow) * K + scol;
  const u16* agp1 = A  + (size_t)(brow + srow + 16) * K + scol;
  const u16* bgp0 = Bt + (size_t)(bcol + srow) * K + scol;
  const u16* bgp1 = Bt + (size_t)(bcol + srow + 16) * K + scol;
  const int lo0 = wave * 1024, lo1 = wave * 1024 + 512;
  const int nk = K >> 5;
  // prologue: stage K-step 0 into buffer 0
  gld16(agp0, &As[0][lo0]);
  gld16(agp1, &As[0][lo1]);
  gld16(bgp0, &Bs[0][lo0]);
  gld16(bgp1, &Bs[0][lo1]);
  for (int ks = 0; ks < nk; ++ks) {
    const int cur = ks & 1;
    if (ks + 1 < nk) {
      const int k1 = (ks + 1) << 5;
      gld16(agp0 + k1, &As[cur ^ 1][lo0]);
      gld16(agp1 + k1, &As[cur ^ 1][lo1]);
      gld16(bgp0 + k1, &Bs[cur ^ 1][lo0]);
      gld16(bgp1 + k1, &Bs[cur ^ 1][lo1]);
      asm volatile("s_waitcnt vmcnt(4)" ::: "memory");
    } else {
      asm volatile("s_waitcnt vmcnt(0)" ::: "memory");
    }
    __builtin_amdgcn_s_barrier();
    __builtin_amdgcn_sched_barrier(0);
    bf16x8 af[4], bfr[4];
    #pragma unroll
    for (int mi = 0; mi < 4; ++mi)
      af[mi] = *reinterpret_cast<const bf16x8*>(&As[cur][(wr + mi * 16 + c) * 32 + g * 8]);
    #pragma unroll
    for (int ni = 0; ni < 4; ++ni)
      bfr[ni] = *reinterpret_cast<const bf16x8*>(&Bs[cur][(wc + ni * 16 + c) * 32 + g * 8]);
    #pragma unroll
    for (int mi = 0; mi < 4; ++mi)
      #pragma unroll
      for (int ni = 0; ni < 4; ++ni)
        acc[mi][ni] = MFMA16(af[mi], bfr[ni], acc[mi][ni]);
    __builtin_amdgcn_sched_barrier(0);
    __builtin_amdgcn_s_barrier();
  }
  #pragma unroll
  for (int mi = 0; mi < 4; ++mi) {
    #pragma unroll
    for (int ni = 0; ni < 4; ++ni) {
      const int col = bcol + wc + ni * 16 + c;
      const float bz = bias[col];
      #pragma unroll
      for (int i = 0; i < 4; ++i) {
        const int row = brow + wr + mi * 16 + g * 4 + i;
        float v = acc[mi][ni][i] + bz;
        if (EPI == 0) {
          if (col < 768)       oq[(size_t)row * 768 + col]        = f2bf(v);
          else if (col < 1536) ok[(size_t)row * 768 + col - 768]  = f2bf(v);
          else                 ov[(size_t)row * 768 + col - 1536] = f2bf(v);
        } else {
          of[(size_t)row * 768 + col] = v;
        }
      }
    }
  }
}

// ---------------- 2x2 max-pool on q (bf16) + fold scale*log2e ----------------
__global__ void qpool(const u16* __restrict__ qf, u16* __restrict__ qp) {
  int idx = blockIdx.x * blockDim.x + threadIdx.x;
  if (idx >= 4096 * 96) return;
  const float SC = 0.14724744f;  // 96^-0.5 * log2(e)
  int r = idx / 96, cc = (idx - r * 96) * 8;
  int b = r >> 10, ij = r & 1023, ii = ij >> 5, jj = ij & 31;
  const size_t base = ((size_t)b * 4096 + (size_t)ii * 128 + jj * 2) * 768 + cc;
  u16x8 x0 = *reinterpret_cast<const u16x8*>(qf + base);
  u16x8 x1 = *reinterpret_cast<const u16x8*>(qf + base + 768);
  u16x8 x2 = *reinterpret_cast<const u16x8*>(qf + base + 64 * 768);
  u16x8 x3 = *reinterpret_cast<const u16x8*>(qf + base + 65 * 768);
  u16x8 o;
  #pragma unroll
  for (int e = 0; e < 8; ++e) {
    float mv = bf2f(x0[e]);
    mv = fmaxf(mv, bf2f(x1[e]));
    mv = fmaxf(mv, bf2f(x2[e]));
    mv = fmaxf(mv, bf2f(x3[e]));
    o[e] = f2bf(mv * SC);
  }
  *reinterpret_cast<u16x8*>(qp + (size_t)r * 768 + cc) = o;
}

// ---------------- V transpose: vbuf[16384][768] -> vT[(bh*96+d)*4096 + sp] ----------------
__global__ void vtrans(const u16* __restrict__ vbuf, u16* __restrict__ vT) {
  __shared__ u16 T[64][97];
  const int blk = blockIdx.x;           // (bh)*64 + tile
  const int st = blk & 63, bh = blk >> 6;
  const int b = bh >> 3, h = bh & 7;
  const int tid = threadIdx.x;
  const u16* src = vbuf + ((size_t)(b * 4096 + st * 64)) * 768 + h * 96;
  #pragma unroll
  for (int j = 0; j < 3; ++j) {
    int p = tid + 256 * j;              // 0..767
    int r = p / 12, ch = p - r * 12;
    u16x8 v = *reinterpret_cast<const u16x8*>(src + (size_t)r * 768 + ch * 8);
    #pragma unroll
    for (int e = 0; e < 8; ++e) T[r][ch * 8 + e] = v[e];
  }
  __syncthreads();
  u16* dst = vT + ((size_t)(bh * 96)) * 4096 + st * 64;
  #pragma unroll
  for (int j = 0; j < 3; ++j) {
    int oc = tid + 256 * j;             // 0..767
    int d = oc >> 3, part = oc & 7;
    u16x8 o;
    #pragma unroll
    for (int e = 0; e < 8; ++e) o[e] = T[part * 8 + e][d];
    *reinterpret_cast<u16x8*>(dst + (size_t)d * 4096 + part * 8) = o;
  }
}

// ---------------- flash attention, swapped-QK^T, dbuf prefetch, KVBLK=64, split x2 ----------------
// grid 1024: blk = ((bh*16 + qt) * 2 + sp). 4 waves; wave w owns q rows qt*64+w*16..+15.
__launch_bounds__(256)
__global__ void flash4(const u16* __restrict__ Qp, const u16* __restrict__ Kb,
                       const u16* __restrict__ Vtg,
                       float* __restrict__ pacc, float* __restrict__ pml) {
  const int blk = blockIdx.x;
  const int sp = blk & 1, qt = (blk >> 1) & 15, bh = blk >> 5;
  const int b = bh >> 3, h = bh & 7;
  __shared__ __align__(16) u16 Ks[2][64 * 96];   // natural [key][96]
  __shared__ __align__(16) u16 Vs[2][96 * 64];   // [d][64 keys], chunk-swizzled by d&7
  __shared__ __align__(16) u16 Pl[4 * 16 * 64];  // per-wave [16 q][64 keys], 8B-chunk swz
  const int tid = threadIdx.x, w = tid >> 6, lane = tid & 63;
  const int c = lane & 15, g = lane >> 4;
  // Q fragments (pre-scaled by scale*log2e); q = c
  const u16* qb = Qp + ((size_t)(b * 1024 + qt * 64 + w * 16 + c)) * 768 + h * 96;
  bf16x8 qf[3];
  #pragma unroll
  for (int kc = 0; kc < 3; ++kc)
    qf[kc] = *reinterpret_cast<const bf16x8*>(qb + kc * 32 + g * 8);
  // staging thread-constants
  int koff[3], voff[3], loff[3];
  #pragma unroll
  for (int j = 0; j < 3; ++j) {
    int p = w * 192 + j * 64 + lane;    // 0..767
    int r = p / 12, ch = p - r * 12;    // K: row r, chunk ch (12 x 16B per row)
    koff[j] = r * 768 + ch * 8;
    int d = p >> 3, vch = p & 7;        // V: row d (8 x 16B per row), pre-swizzled src
    voff[j] = d * 4096 + ((vch ^ (d & 7)) * 8);
    loff[j] = (w * 192 + j * 64) * 8;   // wave-uniform LDS base (u16 idx)
  }
  const u16* kb0 = Kb + ((size_t)(b * 4096 + sp * 2048)) * 768 + h * 96;
  const u16* vb0 = Vtg + ((size_t)(bh * 96)) * 4096 + sp * 2048;
  float m = -1e30f, l = 0.f;            // per-lane, q = c domain (replicated over g)
  f32x4 acc[6] = {};
  const int sw = (c & 7) << 3;          // Vs read-side chunk swizzle (u16 index)
  const int psw = (c & 7) << 1;         // Pl 8B-chunk swizzle (even -> keeps pairs)
  const int pbase = w * 1024 + c * 64;
  // prologue: stage tile 0 into buffer 0
  #pragma unroll
  for (int j = 0; j < 3; ++j) gld16(kb0 + koff[j], &Ks[0][loff[j]]);
  #pragma unroll
  for (int j = 0; j < 3; ++j) gld16(vb0 + voff[j], &Vs[0][loff[j]]);
  for (int kt = 0; kt < 32; ++kt) {
    const int cur = kt & 1;
    if (kt < 31) {
      #pragma unroll
      for (int j = 0; j < 3; ++j)
        gld16(kb0 + (size_t)(kt + 1) * 49152 + koff[j], &Ks[cur ^ 1][loff[j]]);
      #pragma unroll
      for (int j = 0; j < 3; ++j)
        gld16(vb0 + (kt + 1) * 64 + voff[j], &Vs[cur ^ 1][loff[j]]);
      asm volatile("s_waitcnt vmcnt(6)" ::: "memory");
    } else {
      asm volatile("s_waitcnt vmcnt(0)" ::: "memory");
    }
    __builtin_amdgcn_s_barrier();
    __builtin_amdgcn_sched_barrier(0);
    // swapped QK^T: st[kt4] = S^T[key = kt4*16 + g*4 + i][q = c]
    f32x4 st[4] = {};
    #pragma unroll
    for (int kc = 0; kc < 3; ++kc)
      #pragma unroll
      for (int kt4 = 0; kt4 < 4; ++kt4) {
        bf16x8 kf = *reinterpret_cast<const bf16x8*>(&Ks[cur][(kt4 * 16 + c) * 96 + kc * 32 + g * 8]);
        st[kt4] = MFMA16(kf, qf[kc], st[kt4]);
      }
    // per-lane max over 16 in-register keys, then cross-g (2 shfl)
    float pmax = st[0][0];
    #pragma unroll
    for (int kt4 = 0; kt4 < 4; ++kt4)
      #pragma unroll
      for (int i = 0; i < 4; ++i)
        pmax = fmaxf(pmax, st[kt4][i]);
    pmax = fmaxf(pmax, __shfl_xor(pmax, 16));
    pmax = fmaxf(pmax, __shfl_xor(pmax, 32));
    // defer-max: rescale only when max grew past threshold (wave-uniform branch)
    if (__any(pmax > m + 8.0f)) {
      float mn = fmaxf(m, pmax);
      float esc = exp2f(m - mn);
      m = mn;
      l *= esc;
      float er[4];
      #pragma unroll
      for (int i = 0; i < 4; ++i) er[i] = __shfl(esc, g * 4 + i);  // esc for acc row q=g*4+i
      #pragma unroll
      for (int dc = 0; dc < 6; ++dc)
        #pragma unroll
        for (int i = 0; i < 4; ++i)
          acc[dc][i] *= er[i];
    }
    // P = exp2(S - m), row-sum (in-lane + 2 shfl)
    float ps = 0.f;
    #pragma unroll
    for (int kt4 = 0; kt4 < 4; ++kt4)
      #pragma unroll
      for (int i = 0; i < 4; ++i) {
        float p = exp2f(st[kt4][i] - m);
        st[kt4][i] = p;
        ps += p;
      }
    ps += __shfl_xor(ps, 16);
    ps += __shfl_xor(ps, 32);
    l += ps;
    // pack P -> bf16 pairs, write 4 keys (8B) per kt4 into swizzled Pl row q=c
    #pragma unroll
    for (int kt4 = 0; kt4 < 4; ++kt4) {
      unsigned int u0, u1;
      asm("v_cvt_pk_bf16_f32 %0, %1, %2" : "=v"(u0) : "v"(st[kt4][0]), "v"(st[kt4][1]));
      asm("v_cvt_pk_bf16_f32 %0, %1, %2" : "=v"(u1) : "v"(st[kt4][2]), "v"(st[kt4][3]));
      const int chunk = (kt4 * 4 + g) ^ psw;
      *reinterpret_cast<uint2*>(&Pl[pbase + chunk * 4]) = make_uint2(u0, u1);
    }
    asm volatile("s_waitcnt lgkmcnt(0)" ::: "memory");  // per-wave P write->read ordering
    // PV: acc[dc] += P * V   (acc row = q = g*4+i, col d = dc*16+c)
    #pragma unroll
    for (int kh = 0; kh < 2; ++kh) {
      const int rchunk = (kh * 8 + g * 2) ^ psw;
      bf16x8 pf = *reinterpret_cast<const bf16x8*>(&Pl[pbase + rchunk * 4]);
      #pragma unroll
      for (int dc = 0; dc < 6; ++dc) {
        bf16x8 vf = *reinterpret_cast<const bf16x8*>(&Vs[cur][(dc * 16 + c) * 64 + ((kh * 32 + g * 8) ^ sw)]);
        acc[dc] = MFMA16(pf, vf, acc[dc]);
      }
    }
    __builtin_amdgcn_sched_barrier(0);
    __builtin_amdgcn_s_barrier();
  }
  // write partial (unnormalized acc, m, l)
  const int prow = blk * 64 + w * 16;
  #pragma unroll
  for (int dc = 0; dc < 6; ++dc)
    #pragma unroll
    for (int i = 0; i < 4; ++i)
      pacc[(size_t)(prow + g * 4 + i) * 96 + dc * 16 + c] = acc[dc][i];
  if (lane < 16) {
    pml[(prow + lane) * 2]     = m;
    pml[(prow + lane) * 2 + 1] = l;
  }
}

// ---------------- combine 2 key-splits -> aout (bf16) ----------------
__global__ void fcomb(const float* __restrict__ pacc, const float* __restrict__ pml,
                      u16* __restrict__ aout) {
  const int bhqt = blockIdx.x;          // 512
  const int qt = bhqt & 15, bh = bhqt >> 4;
  const int b = bh >> 3, h = bh & 7;
  const int p0 = bhqt * 2, p1 = p0 + 1;
  const int tid = threadIdx.x;
  #pragma unroll
  for (int j = 0; j < 6; ++j) {
    int idx = tid + 256 * j;            // 0..1535 f32x4 chunks
    int r = idx / 24, dq = idx - r * 24;
    float m0 = pml[(p0 * 64 + r) * 2], l0 = pml[(p0 * 64 + r) * 2 + 1];
    float m1 = pml[(p1 * 64 + r) * 2], l1 = pml[(p1 * 64 + r) * 2 + 1];
    float M = fmaxf(m0, m1);
    float e0 = exp2f(m0 - M), e1 = exp2f(m1 - M);
    float inv = 1.f / (l0 * e0 + l1 * e1);
    f32x4 a0 = *reinterpret_cast<const f32x4*>(pacc + ((size_t)(p0 * 64 + r)) * 96 + dq * 4);
    f32x4 a1 = *reinterpret_cast<const f32x4*>(pacc + ((size_t)(p1 * 64 + r)) * 96 + dq * 4);
    ushort4 o;
    o.x = f2bf((a0[0] * e0 + a1[0] * e1) * inv);
    o.y = f2bf((a0[1] * e0 + a1[1] * e1) * inv);
    o.z = f2bf((a0[2] * e0 + a1[2] * e1) * inv);
    o.w = f2bf((a0[3] * e0 + a1[3] * e1) * inv);
    *reinterpret_cast<ushort4*>(aout + (size_t)(b * 1024 + qt * 64 + r) * 768 + h * 96 + dq * 4) = o;
  }
}

extern "C" void kernel_launch(void* const* d_in, const int* in_sizes, int n_in,
                              void* d_out, int out_size, void* d_ws, size_t ws_size,
                              hipStream_t stream) {
  const float* hs     = (const float*)d_in[0];
  const float* qkv_w  = (const float*)d_in[1];
  const float* qkv_b  = (const float*)d_in[2];
  const float* proj_w = (const float*)d_in[3];
  const float* proj_b = (const float*)d_in[4];
  float* out = (float*)d_out;

  u16* hs_bf  = (u16*)d_ws;                 // 6291456 u16 (dead after gemm<0>) -> pml
  u16* qkvwT  = hs_bf  + 6291456;           // 884736
  u16* projwT = qkvwT  + 884736;            // 589824
  u16* qfull  = projwT + 589824;            // 12582912 (dead after qpool) -> vT
  u16* kbuf   = qfull  + 12582912;          // 12582912
  u16* vbuf   = kbuf   + 12582912;          // 12582912 (dead after vtrans) -> pacc
  u16* qpol   = vbuf   + 12582912;          // 3145728
  u16* aout   = qpol   + 3145728;           // 3145728

  u16* vT     = qfull;                      // 32*96*4096 = 12582912 u16, exact fit
  float* pacc = (float*)vbuf;               // 1024*64*96*4B = 25165824 B, exact fit
  float* pml  = (float*)hs_bf;              // 524288 B

  cast4<<<6144, 256, 0, stream>>>(hs, hs_bf, 1572864);
  tcast<<<3456, 256, 0, stream>>>(qkv_w, qkvwT, 384, 2304);
  tcast<<<2304, 256, 0, stream>>>(proj_w, projwT, 768, 768);

  gemm_bt<0><<<dim3(18, 128), 256, 0, stream>>>(hs_bf, qkvwT, qkv_b,
                                                qfull, kbuf, vbuf, nullptr, 384);
  qpool<<<1536, 256, 0, stream>>>(qfull, qpol);
  vtrans<<<2048, 256, 0, stream>>>(vbuf, vT);
  flash4<<<1024, 256, 0, stream>>>(qpol, kbuf, vT, pacc, pml);
  fcomb<<<512, 256, 0, stream>>>(pacc, pml, aout);
  gemm_bt<1><<<dim3(6, 32), 256, 0, stream>>>(aout, projwT, proj_b,
                                              nullptr, nullptr, nullptr, out, 768);
}

// Round 6
// 206.894 us; speedup vs baseline: 3.8641x; 1.1411x over previous
//
#include <hip/hip_runtime.h>
#include <hip/hip_bf16.h>

typedef unsigned short u16;
typedef __attribute__((ext_vector_type(8))) short bf16x8;
typedef __attribute__((ext_vector_type(8))) unsigned short u16x8;
typedef __attribute__((ext_vector_type(4))) float f32x4;

#define MFMA16(a,b,c) __builtin_amdgcn_mfma_f32_16x16x32_bf16(a,b,c,0,0,0)

__device__ __forceinline__ u16 f2bf(float f) {
  union { float f; unsigned int u; } v; v.f = f;
  unsigned int r = v.u + 0x7fffu + ((v.u >> 16) & 1u);  // RNE, finite inputs
  return (u16)(r >> 16);
}
__device__ __forceinline__ float bf2f(u16 u) {
  union { unsigned int i; float f; } v; v.i = ((unsigned int)u) << 16; return v.f;
}

__device__ __forceinline__ void gld16(const void* g, void* l) {
  __builtin_amdgcn_global_load_lds((const __attribute__((address_space(1))) void*)g,
                                   (__attribute__((address_space(3))) void*)l, 16, 0, 0);
}

// ---------------- cast fp32 -> bf16 (4/thread) ----------------
__global__ void cast4(const float* __restrict__ in, u16* __restrict__ out, int n4) {
  int i = blockIdx.x * blockDim.x + threadIdx.x;
  if (i >= n4) return;
  float4 v = reinterpret_cast<const float4*>(in)[i];
  ushort4 o; o.x = f2bf(v.x); o.y = f2bf(v.y); o.z = f2bf(v.z); o.w = f2bf(v.w);
  reinterpret_cast<ushort4*>(out)[i] = o;
}

// ---------------- transpose-cast weight: out[n*K+k] = bf16(in[k*N+n]) ----------------
__global__ void tcast(const float* __restrict__ in, u16* __restrict__ out, int K, int N) {
  int idx = blockIdx.x * blockDim.x + threadIdx.x;
  if (idx >= K * N) return;
  int n = idx / K, k = idx - n * K;
  out[idx] = f2bf(in[(size_t)k * N + n]);
}

// ---------------- GEMM: C[M,N] = A[M,K] * Bt[N,K]^T + bias ----------------
// 128x128 tile, BK=32, double-buffered LDS, counted-vmcnt prefetch pipeline.
template<int EPI>
__launch_bounds__(256)
__global__ void gemm_bt(const u16* __restrict__ A, const u16* __restrict__ Bt,
                        const float* __restrict__ bias,
                        u16* __restrict__ oq, u16* __restrict__ ok, u16* __restrict__ ov,
                        float* __restrict__ of, int K) {
  __shared__ __align__(16) u16 As[2][128 * 32];
  __shared__ __align__(16) u16 Bs[2][128 * 32];
  const int tid = threadIdx.x;
  const int wave = tid >> 6, lane = tid & 63;
  const int c = lane & 15, g = lane >> 4;
  const int brow = blockIdx.y * 128, bcol = blockIdx.x * 128;
  const int wr = (wave >> 1) * 64, wc = (wave & 1) * 64;
  f32x4 acc[4][4] = {};
  const int srow = wave * 32 + (lane >> 2);
  const int scol = (lane & 3) * 8;
  const u16* agp0 = A  + (size_t)(brow + srow) * K + scol;
  const u16* agp1 = A  + (size_t)(brow + srow + 16) * K + scol;
  const u16* bgp0 = Bt + (size_t)(bcol + srow) * K + scol;
  const u16* bgp1 = Bt + (size_t)(bcol + srow + 16) * K + scol;
  const int lo0 = wave * 1024, lo1 = wave * 1024 + 512;
  const int nk = K >> 5;
  // prologue: stage K-step 0 into buffer 0
  gld16(agp0, &As[0][lo0]);
  gld16(agp1, &As[0][lo1]);
  gld16(bgp0, &Bs[0][lo0]);
  gld16(bgp1, &Bs[0][lo1]);
  for (int ks = 0; ks < nk; ++ks) {
    const int cur = ks & 1;
    if (ks + 1 < nk) {
      const int k1 = (ks + 1) << 5;
      gld16(agp0 + k1, &As[cur ^ 1][lo0]);
      gld16(agp1 + k1, &As[cur ^ 1][lo1]);
      gld16(bgp0 + k1, &Bs[cur ^ 1][lo0]);
      gld16(bgp1 + k1, &Bs[cur ^ 1][lo1]);
      asm volatile("s_waitcnt vmcnt(4)" ::: "memory");
    } else {
      asm volatile("s_waitcnt vmcnt(0)" ::: "memory");
    }
    __builtin_amdgcn_s_barrier();
    __builtin_amdgcn_sched_barrier(0);
    bf16x8 af[4], bfr[4];
    #pragma unroll
    for (int mi = 0; mi < 4; ++mi)
      af[mi] = *reinterpret_cast<const bf16x8*>(&As[cur][(wr + mi * 16 + c) * 32 + g * 8]);
    #pragma unroll
    for (int ni = 0; ni < 4; ++ni)
      bfr[ni] = *reinterpret_cast<const bf16x8*>(&Bs[cur][(wc + ni * 16 + c) * 32 + g * 8]);
    #pragma unroll
    for (int mi = 0; mi < 4; ++mi)
      #pragma unroll
      for (int ni = 0; ni < 4; ++ni)
        acc[mi][ni] = MFMA16(af[mi], bfr[ni], acc[mi][ni]);
    __builtin_amdgcn_sched_barrier(0);
    __builtin_amdgcn_s_barrier();
  }
  #pragma unroll
  for (int mi = 0; mi < 4; ++mi) {
    #pragma unroll
    for (int ni = 0; ni < 4; ++ni) {
      const int col = bcol + wc + ni * 16 + c;
      const float bz = bias[col];
      #pragma unroll
      for (int i = 0; i < 4; ++i) {
        const int row = brow + wr + mi * 16 + g * 4 + i;
        float v = acc[mi][ni][i] + bz;
        if (EPI == 0) {
          if (col < 768)       oq[(size_t)row * 768 + col]        = f2bf(v);
          else if (col < 1536) ok[(size_t)row * 768 + col - 768]  = f2bf(v);
          else                 ov[(size_t)row * 768 + col - 1536] = f2bf(v);
        } else {
          of[(size_t)row * 768 + col] = v;
        }
      }
    }
  }
}

// ---------------- 2x2 max-pool on q (bf16) + fold scale*log2e ----------------
__global__ void qpool(const u16* __restrict__ qf, u16* __restrict__ qp) {
  int idx = blockIdx.x * blockDim.x + threadIdx.x;
  if (idx >= 4096 * 96) return;
  const float SC = 0.14724744f;  // 96^-0.5 * log2(e)
  int r = idx / 96, cc = (idx - r * 96) * 8;
  int b = r >> 10, ij = r & 1023, ii = ij >> 5, jj = ij & 31;
  const size_t base = ((size_t)b * 4096 + (size_t)ii * 128 + jj * 2) * 768 + cc;
  u16x8 x0 = *reinterpret_cast<const u16x8*>(qf + base);
  u16x8 x1 = *reinterpret_cast<const u16x8*>(qf + base + 768);
  u16x8 x2 = *reinterpret_cast<const u16x8*>(qf + base + 64 * 768);
  u16x8 x3 = *reinterpret_cast<const u16x8*>(qf + base + 65 * 768);
  u16x8 o;
  #pragma unroll
  for (int e = 0; e < 8; ++e) {
    float mv = bf2f(x0[e]);
    mv = fmaxf(mv, bf2f(x1[e]));
    mv = fmaxf(mv, bf2f(x2[e]));
    mv = fmaxf(mv, bf2f(x3[e]));
    o[e] = f2bf(mv * SC);
  }
  *reinterpret_cast<u16x8*>(qp + (size_t)r * 768 + cc) = o;
}

// ---------------- V transpose: vbuf[16384][768] -> vT[(bh*96+d)*4096 + sp] ----------------
__global__ void vtrans(const u16* __restrict__ vbuf, u16* __restrict__ vT) {
  __shared__ u16 T[64][97];
  const int blk = blockIdx.x;           // (bh)*64 + tile
  const int st = blk & 63, bh = blk >> 6;
  const int b = bh >> 3, h = bh & 7;
  const int tid = threadIdx.x;
  const u16* src = vbuf + ((size_t)(b * 4096 + st * 64)) * 768 + h * 96;
  #pragma unroll
  for (int j = 0; j < 3; ++j) {
    int p = tid + 256 * j;              // 0..767
    int r = p / 12, ch = p - r * 12;
    u16x8 v = *reinterpret_cast<const u16x8*>(src + (size_t)r * 768 + ch * 8);
    #pragma unroll
    for (int e = 0; e < 8; ++e) T[r][ch * 8 + e] = v[e];
  }
  __syncthreads();
  u16* dst = vT + ((size_t)(bh * 96)) * 4096 + st * 64;
  #pragma unroll
  for (int j = 0; j < 3; ++j) {
    int oc = tid + 256 * j;             // 0..767
    int d = oc >> 3, part = oc & 7;
    u16x8 o;
    #pragma unroll
    for (int e = 0; e < 8; ++e) o[e] = T[part * 8 + e][d];
    *reinterpret_cast<u16x8*>(dst + (size_t)d * 4096 + part * 8) = o;
  }
}

// ---------------- flash attention, swapped-QK^T, single-buf, 4-blocks/CU, split x2 ----------------
// grid 1024: blk = ((bh*16 + qt) * 2 + sp). 4 waves; wave w owns q rows qt*64+w*16..+15.
// __launch_bounds__(256,4): cap regs at 128/wave so 4 blocks (16 waves) fit per CU.
__launch_bounds__(256, 4)
__global__ void flash5(const u16* __restrict__ Qp, const u16* __restrict__ Kb,
                       const u16* __restrict__ Vtg,
                       float* __restrict__ pacc, float* __restrict__ pml) {
  const int blk = blockIdx.x;
  const int sp = blk & 1, qt = (blk >> 1) & 15, bh = blk >> 5;
  const int b = bh >> 3, h = bh & 7;
  __shared__ __align__(16) u16 Ks[64 * 96];      // natural [key][96]
  __shared__ __align__(16) u16 Vs[96 * 64];      // [d][64 keys], chunk-swizzled by d&7
  __shared__ __align__(16) u16 Pl[4 * 16 * 64];  // per-wave [16 q][64 keys], 8B-chunk swz
  const int tid = threadIdx.x, w = tid >> 6, lane = tid & 63;
  const int c = lane & 15, g = lane >> 4;
  // Q fragments (pre-scaled by scale*log2e); q = c
  const u16* qb = Qp + ((size_t)(b * 1024 + qt * 64 + w * 16 + c)) * 768 + h * 96;
  bf16x8 qf[3];
  #pragma unroll
  for (int kc = 0; kc < 3; ++kc)
    qf[kc] = *reinterpret_cast<const bf16x8*>(qb + kc * 32 + g * 8);
  // staging thread-constants (LDS offsets as 32-bit ints, wave-uniform base + lane*16B)
  int koff[3], voff[3], loff[3];
  #pragma unroll
  for (int j = 0; j < 3; ++j) {
    int p = w * 192 + j * 64 + lane;    // 0..767
    int r = p / 12, ch = p - r * 12;    // K: row r, chunk ch (12 x 16B per row)
    koff[j] = r * 768 + ch * 8;
    int d = p >> 3, vch = p & 7;        // V: row d (8 x 16B per row), pre-swizzled src
    voff[j] = d * 4096 + ((vch ^ (d & 7)) * 8);
    loff[j] = (w * 192 + j * 64) * 8;   // wave-uniform LDS base (u16 idx)
  }
  const u16* kb0 = Kb + ((size_t)(b * 4096 + sp * 2048)) * 768 + h * 96;
  const u16* vb0 = Vtg + ((size_t)(bh * 96)) * 4096 + sp * 2048;
  float m = -1e30f, l = 0.f;            // per-lane, q = c domain (replicated over g)
  f32x4 acc[6] = {};
  const int sw = (c & 7) << 3;          // Vs read-side chunk swizzle (u16 index)
  const int psw = (c & 7) << 1;         // Pl 8B-chunk swizzle (even -> keeps pairs)
  const int pbase = w * 1024 + c * 64;
  for (int kt = 0; kt < 32; ++kt) {
    __syncthreads();
    #pragma unroll
    for (int j = 0; j < 3; ++j) gld16(kb0 + (size_t)kt * 49152 + koff[j], &Ks[loff[j]]);
    #pragma unroll
    for (int j = 0; j < 3; ++j) gld16(vb0 + kt * 64 + voff[j], &Vs[loff[j]]);
    __syncthreads();
    // swapped QK^T: st[kt4] = S^T[key = kt4*16 + g*4 + i][q = c]
    f32x4 st[4] = {};
    #pragma unroll
    for (int kc = 0; kc < 3; ++kc)
      #pragma unroll
      for (int kt4 = 0; kt4 < 4; ++kt4) {
        bf16x8 kf = *reinterpret_cast<const bf16x8*>(&Ks[(kt4 * 16 + c) * 96 + kc * 32 + g * 8]);
        st[kt4] = MFMA16(kf, qf[kc], st[kt4]);
      }
    // per-lane max over 16 in-register keys, then cross-g (2 shfl)
    float pmax = st[0][0];
    #pragma unroll
    for (int kt4 = 0; kt4 < 4; ++kt4)
      #pragma unroll
      for (int i = 0; i < 4; ++i)
        pmax = fmaxf(pmax, st[kt4][i]);
    pmax = fmaxf(pmax, __shfl_xor(pmax, 16));
    pmax = fmaxf(pmax, __shfl_xor(pmax, 32));
    // defer-max: rescale only when max grew past threshold (wave-uniform branch)
    if (__any(pmax > m + 8.0f)) {
      float mn = fmaxf(m, pmax);
      float esc = exp2f(m - mn);
      m = mn;
      l *= esc;
      float er[4];
      #pragma unroll
      for (int i = 0; i < 4; ++i) er[i] = __shfl(esc, g * 4 + i);  // esc for acc row q=g*4+i
      #pragma unroll
      for (int dc = 0; dc < 6; ++dc)
        #pragma unroll
        for (int i = 0; i < 4; ++i)
          acc[dc][i] *= er[i];
    }
    // P = exp2(S - m), row-sum (in-lane + 2 shfl)
    float ps = 0.f;
    #pragma unroll
    for (int kt4 = 0; kt4 < 4; ++kt4)
      #pragma unroll
      for (int i = 0; i < 4; ++i) {
        float p = exp2f(st[kt4][i] - m);
        st[kt4][i] = p;
        ps += p;
      }
    ps += __shfl_xor(ps, 16);
    ps += __shfl_xor(ps, 32);
    l += ps;
    // pack P -> bf16 pairs, write 4 keys (8B) per kt4 into swizzled Pl row q=c
    #pragma unroll
    for (int kt4 = 0; kt4 < 4; ++kt4) {
      unsigned int u0, u1;
      asm("v_cvt_pk_bf16_f32 %0, %1, %2" : "=v"(u0) : "v"(st[kt4][0]), "v"(st[kt4][1]));
      asm("v_cvt_pk_bf16_f32 %0, %1, %2" : "=v"(u1) : "v"(st[kt4][2]), "v"(st[kt4][3]));
      const int chunk = (kt4 * 4 + g) ^ psw;
      *reinterpret_cast<uint2*>(&Pl[pbase + chunk * 4]) = make_uint2(u0, u1);
    }
    asm volatile("s_waitcnt lgkmcnt(0)" ::: "memory");  // per-wave P write->read ordering
    // PV: acc[dc] += P * V   (acc row = q = g*4+i, col d = dc*16+c)
    #pragma unroll
    for (int kh = 0; kh < 2; ++kh) {
      const int rchunk = (kh * 8 + g * 2) ^ psw;
      bf16x8 pf = *reinterpret_cast<const bf16x8*>(&Pl[pbase + rchunk * 4]);
      #pragma unroll
      for (int dc = 0; dc < 6; ++dc) {
        bf16x8 vf = *reinterpret_cast<const bf16x8*>(&Vs[(dc * 16 + c) * 64 + ((kh * 32 + g * 8) ^ sw)]);
        acc[dc] = MFMA16(pf, vf, acc[dc]);
      }
    }
  }
  // write partial (unnormalized acc, m, l)
  const int prow = blk * 64 + w * 16;
  #pragma unroll
  for (int dc = 0; dc < 6; ++dc)
    #pragma unroll
    for (int i = 0; i < 4; ++i)
      pacc[(size_t)(prow + g * 4 + i) * 96 + dc * 16 + c] = acc[dc][i];
  if (lane < 16) {
    pml[(prow + lane) * 2]     = m;
    pml[(prow + lane) * 2 + 1] = l;
  }
}

// ---------------- combine 2 key-splits -> aout (bf16) ----------------
__global__ void fcomb(const float* __restrict__ pacc, const float* __restrict__ pml,
                      u16* __restrict__ aout) {
  const int bhqt = blockIdx.x;          // 512
  const int qt = bhqt & 15, bh = bhqt >> 4;
  const int b = bh >> 3, h = bh & 7;
  const int p0 = bhqt * 2, p1 = p0 + 1;
  const int tid = threadIdx.x;
  #pragma unroll
  for (int j = 0; j < 6; ++j) {
    int idx = tid + 256 * j;            // 0..1535 f32x4 chunks
    int r = idx / 24, dq = idx - r * 24;
    float m0 = pml[(p0 * 64 + r) * 2], l0 = pml[(p0 * 64 + r) * 2 + 1];
    float m1 = pml[(p1 * 64 + r) * 2], l1 = pml[(p1 * 64 + r) * 2 + 1];
    float M = fmaxf(m0, m1);
    float e0 = exp2f(m0 - M), e1 = exp2f(m1 - M);
    float inv = 1.f / (l0 * e0 + l1 * e1);
    f32x4 a0 = *reinterpret_cast<const f32x4*>(pacc + ((size_t)(p0 * 64 + r)) * 96 + dq * 4);
    f32x4 a1 = *reinterpret_cast<const f32x4*>(pacc + ((size_t)(p1 * 64 + r)) * 96 + dq * 4);
    ushort4 o;
    o.x = f2bf((a0[0] * e0 + a1[0] * e1) * inv);
    o.y = f2bf((a0[1] * e0 + a1[1] * e1) * inv);
    o.z = f2bf((a0[2] * e0 + a1[2] * e1) * inv);
    o.w = f2bf((a0[3] * e0 + a1[3] * e1) * inv);
    *reinterpret_cast<ushort4*>(aout + (size_t)(b * 1024 + qt * 64 + r) * 768 + h * 96 + dq * 4) = o;
  }
}

extern "C" void kernel_launch(void* const* d_in, const int* in_sizes, int n_in,
                              void* d_out, int out_size, void* d_ws, size_t ws_size,
                              hipStream_t stream) {
  const float* hs     = (const float*)d_in[0];
  const float* qkv_w  = (const float*)d_in[1];
  const float* qkv_b  = (const float*)d_in[2];
  const float* proj_w = (const float*)d_in[3];
  const float* proj_b = (const float*)d_in[4];
  float* out = (float*)d_out;

  u16* hs_bf  = (u16*)d_ws;                 // 6291456 u16 (dead after gemm<0>) -> pml
  u16* qkvwT  = hs_bf  + 6291456;           // 884736
  u16* projwT = qkvwT  + 884736;            // 589824
  u16* qfull  = projwT + 589824;            // 12582912 (dead after qpool) -> vT
  u16* kbuf   = qfull  + 12582912;          // 12582912
  u16* vbuf   = kbuf   + 12582912;          // 12582912 (dead after vtrans) -> pacc
  u16* qpol   = vbuf   + 12582912;          // 3145728
  u16* aout   = qpol   + 3145728;           // 3145728

  u16* vT     = qfull;                      // 32*96*4096 = 12582912 u16, exact fit
  float* pacc = (float*)vbuf;               // 1024*64*96*4B = 25165824 B, exact fit
  float* pml  = (float*)hs_bf;              // 524288 B

  cast4<<<6144, 256, 0, stream>>>(hs, hs_bf, 1572864);
  tcast<<<3456, 256, 0, stream>>>(qkv_w, qkvwT, 384, 2304);
  tcast<<<2304, 256, 0, stream>>>(proj_w, projwT, 768, 768);

  gemm_bt<0><<<dim3(18, 128), 256, 0, stream>>>(hs_bf, qkvwT, qkv_b,
                                                qfull, kbuf, vbuf, nullptr, 384);
  qpool<<<1536, 256, 0, stream>>>(qfull, qpol);
  vtrans<<<2048, 256, 0, stream>>>(vbuf, vT);
  flash5<<<1024, 256, 0, stream>>>(qpol, kbuf, vT, pacc, pml);
  fcomb<<<512, 256, 0, stream>>>(pacc, pml, aout);
  gemm_bt<1><<<dim3(6, 32), 256, 0, stream>>>(aout, projwT, proj_b,
                                              nullptr, nullptr, nullptr, out, 768);
}

// Round 7
// 197.697 us; speedup vs baseline: 4.0439x; 1.0465x over previous
//
#include <hip/hip_runtime.h>
#include <hip/hip_bf16.h>

typedef unsigned short u16;
typedef __attribute__((ext_vector_type(8))) short bf16x8;
typedef __attribute__((ext_vector_type(8))) unsigned short u16x8;
typedef __attribute__((ext_vector_type(4))) float f32x4;

#define MFMA16(a,b,c) __builtin_amdgcn_mfma_f32_16x16x32_bf16(a,b,c,0,0,0)

__device__ __forceinline__ u16 f2bf(float f) {
  union { float f; unsigned int u; } v; v.f = f;
  unsigned int r = v.u + 0x7fffu + ((v.u >> 16) & 1u);  // RNE, finite inputs
  return (u16)(r >> 16);
}
__device__ __forceinline__ float bf2f(u16 u) {
  union { unsigned int i; float f; } v; v.i = ((unsigned int)u) << 16; return v.f;
}

__device__ __forceinline__ void gld16(const void* g, void* l) {
  __builtin_amdgcn_global_load_lds((const __attribute__((address_space(1))) void*)g,
                                   (__attribute__((address_space(3))) void*)l, 16, 0, 0);
}

// ---------------- cast fp32 -> bf16 (4/thread) ----------------
__global__ void cast4(const float* __restrict__ in, u16* __restrict__ out, int n4) {
  int i = blockIdx.x * blockDim.x + threadIdx.x;
  if (i >= n4) return;
  float4 v = reinterpret_cast<const float4*>(in)[i];
  ushort4 o; o.x = f2bf(v.x); o.y = f2bf(v.y); o.z = f2bf(v.z); o.w = f2bf(v.w);
  reinterpret_cast<ushort4*>(out)[i] = o;
}

// ---------------- LDS-tiled transpose-cast: out[n*K+k] = bf16(in[k*N+n]) ----------------
// 64x64 tiles, coalesced float4 loads + u16x8 stores. Requires K%64==0, N%64==0.
__global__ void ttrans(const float* __restrict__ in, u16* __restrict__ out, int K, int N) {
  __shared__ u16 T[64][65];
  const int ntx = N >> 6;
  const int tx = blockIdx.x % ntx, ty = blockIdx.x / ntx;
  const int n0 = tx * 64, k0 = ty * 64;
  const int tid = threadIdx.x;
  #pragma unroll
  for (int p = 0; p < 4; ++p) {
    int idx = p * 256 + tid;            // 0..1023
    int r = idx >> 4, ch = idx & 15;    // row r, 4-f32 chunk ch
    float4 v = *reinterpret_cast<const float4*>(in + (size_t)(k0 + r) * N + n0 + ch * 4);
    T[r][ch * 4 + 0] = f2bf(v.x);
    T[r][ch * 4 + 1] = f2bf(v.y);
    T[r][ch * 4 + 2] = f2bf(v.z);
    T[r][ch * 4 + 3] = f2bf(v.w);
  }
  __syncthreads();
  #pragma unroll
  for (int p = 0; p < 2; ++p) {
    int idx = p * 256 + tid;            // 0..511
    int rr = idx >> 3, ch = idx & 7;    // out row rr, 8-u16 chunk ch
    u16x8 o;
    #pragma unroll
    for (int e = 0; e < 8; ++e) o[e] = T[ch * 8 + e][rr];
    *reinterpret_cast<u16x8*>(out + (size_t)(n0 + rr) * K + k0 + ch * 8) = o;
  }
}

// ---------------- GEMM: C[M,N] = A[M,K] * Bt[N,K]^T + bias ----------------
// 128x128 tile, BK=32, double-buffered LDS, counted-vmcnt prefetch pipeline.
// 1D grid with bijective XCD swizzle (requires nwg%8==0): each XCD gets a
// contiguous chunk of row-panels -> A-panel + B fit its 4MB L2.
template<int EPI>
__launch_bounds__(256)
__global__ void gemm_bt(const u16* __restrict__ A, const u16* __restrict__ Bt,
                        const float* __restrict__ bias,
                        u16* __restrict__ oq, u16* __restrict__ ok, u16* __restrict__ ov,
                        float* __restrict__ of, int K, int nbx, int cpx) {
  __shared__ __align__(16) u16 As[2][128 * 32];
  __shared__ __align__(16) u16 Bs[2][128 * 32];
  const int id = blockIdx.x;
  const int id2 = (id & 7) * cpx + (id >> 3);   // cpx = nwg/8
  const int bx = id2 % nbx, by = id2 / nbx;
  const int tid = threadIdx.x;
  const int wave = tid >> 6, lane = tid & 63;
  const int c = lane & 15, g = lane >> 4;
  const int brow = by * 128, bcol = bx * 128;
  const int wr = (wave >> 1) * 64, wc = (wave & 1) * 64;
  f32x4 acc[4][4] = {};
  const int srow = wave * 32 + (lane >> 2);
  const int scol = (lane & 3) * 8;
  const u16* agp0 = A  + (size_t)(brow + srow) * K + scol;
  const u16* agp1 = A  + (size_t)(brow + srow + 16) * K + scol;
  const u16* bgp0 = Bt + (size_t)(bcol + srow) * K + scol;
  const u16* bgp1 = Bt + (size_t)(bcol + srow + 16) * K + scol;
  const int lo0 = wave * 1024, lo1 = wave * 1024 + 512;
  const int nk = K >> 5;
  gld16(agp0, &As[0][lo0]);
  gld16(agp1, &As[0][lo1]);
  gld16(bgp0, &Bs[0][lo0]);
  gld16(bgp1, &Bs[0][lo1]);
  for (int ks = 0; ks < nk; ++ks) {
    const int cur = ks & 1;
    if (ks + 1 < nk) {
      const int k1 = (ks + 1) << 5;
      gld16(agp0 + k1, &As[cur ^ 1][lo0]);
      gld16(agp1 + k1, &As[cur ^ 1][lo1]);
      gld16(bgp0 + k1, &Bs[cur ^ 1][lo0]);
      gld16(bgp1 + k1, &Bs[cur ^ 1][lo1]);
      asm volatile("s_waitcnt vmcnt(4)" ::: "memory");
    } else {
      asm volatile("s_waitcnt vmcnt(0)" ::: "memory");
    }
    __builtin_amdgcn_s_barrier();
    __builtin_amdgcn_sched_barrier(0);
    bf16x8 af[4], bfr[4];
    #pragma unroll
    for (int mi = 0; mi < 4; ++mi)
      af[mi] = *reinterpret_cast<const bf16x8*>(&As[cur][(wr + mi * 16 + c) * 32 + g * 8]);
    #pragma unroll
    for (int ni = 0; ni < 4; ++ni)
      bfr[ni] = *reinterpret_cast<const bf16x8*>(&Bs[cur][(wc + ni * 16 + c) * 32 + g * 8]);
    #pragma unroll
    for (int mi = 0; mi < 4; ++mi)
      #pragma unroll
      for (int ni = 0; ni < 4; ++ni)
        acc[mi][ni] = MFMA16(af[mi], bfr[ni], acc[mi][ni]);
    __builtin_amdgcn_sched_barrier(0);
    __builtin_amdgcn_s_barrier();
  }
  #pragma unroll
  for (int mi = 0; mi < 4; ++mi) {
    #pragma unroll
    for (int ni = 0; ni < 4; ++ni) {
      const int col = bcol + wc + ni * 16 + c;
      const float bz = bias[col];
      #pragma unroll
      for (int i = 0; i < 4; ++i) {
        const int row = brow + wr + mi * 16 + g * 4 + i;
        float v = acc[mi][ni][i] + bz;
        if (EPI == 0) {
          if (col < 768)       oq[(size_t)row * 768 + col]        = f2bf(v);
          else if (col < 1536) ok[(size_t)row * 768 + col - 768]  = f2bf(v);
          else                 ov[(size_t)row * 768 + col - 1536] = f2bf(v);
        } else {
          of[(size_t)row * 768 + col] = v;
        }
      }
    }
  }
}

// ---------------- 2x2 max-pool on q (bf16) + fold scale*log2e ----------------
__global__ void qpool(const u16* __restrict__ qf, u16* __restrict__ qp) {
  int idx = blockIdx.x * blockDim.x + threadIdx.x;
  if (idx >= 4096 * 96) return;
  const float SC = 0.14724744f;  // 96^-0.5 * log2(e)
  int r = idx / 96, cc = (idx - r * 96) * 8;
  int b = r >> 10, ij = r & 1023, ii = ij >> 5, jj = ij & 31;
  const size_t base = ((size_t)b * 4096 + (size_t)ii * 128 + jj * 2) * 768 + cc;
  u16x8 x0 = *reinterpret_cast<const u16x8*>(qf + base);
  u16x8 x1 = *reinterpret_cast<const u16x8*>(qf + base + 768);
  u16x8 x2 = *reinterpret_cast<const u16x8*>(qf + base + 64 * 768);
  u16x8 x3 = *reinterpret_cast<const u16x8*>(qf + base + 65 * 768);
  u16x8 o;
  #pragma unroll
  for (int e = 0; e < 8; ++e) {
    float mv = bf2f(x0[e]);
    mv = fmaxf(mv, bf2f(x1[e]));
    mv = fmaxf(mv, bf2f(x2[e]));
    mv = fmaxf(mv, bf2f(x3[e]));
    o[e] = f2bf(mv * SC);
  }
  *reinterpret_cast<u16x8*>(qp + (size_t)r * 768 + cc) = o;
}

// ---------------- V transpose: vbuf[16384][768] -> vT[(bh*96+d)*4096 + sp] ----------------
__global__ void vtrans(const u16* __restrict__ vbuf, u16* __restrict__ vT) {
  __shared__ u16 T[64][97];
  const int blk = blockIdx.x;           // (bh)*64 + tile
  const int st = blk & 63, bh = blk >> 6;
  const int b = bh >> 3, h = bh & 7;
  const int tid = threadIdx.x;
  const u16* src = vbuf + ((size_t)(b * 4096 + st * 64)) * 768 + h * 96;
  #pragma unroll
  for (int j = 0; j < 3; ++j) {
    int p = tid + 256 * j;              // 0..767
    int r = p / 12, ch = p - r * 12;
    u16x8 v = *reinterpret_cast<const u16x8*>(src + (size_t)r * 768 + ch * 8);
    #pragma unroll
    for (int e = 0; e < 8; ++e) T[r][ch * 8 + e] = v[e];
  }
  __syncthreads();
  u16* dst = vT + ((size_t)(bh * 96)) * 4096 + st * 64;
  #pragma unroll
  for (int j = 0; j < 3; ++j) {
    int oc = tid + 256 * j;             // 0..767
    int d = oc >> 3, part = oc & 7;
    u16x8 o;
    #pragma unroll
    for (int e = 0; e < 8; ++e) o[e] = T[part * 8 + e][d];
    *reinterpret_cast<u16x8*>(dst + (size_t)d * 4096 + part * 8) = o;
  }
}

// ---------------- flash attention, swapped-QK^T, single-buf, 4-blocks/CU, split x2 ----------------
// grid 1024: blk = ((bh*16 + qt) * 2 + sp). 4 waves; wave w owns q rows qt*64+w*16..+15.
__launch_bounds__(256, 4)
__global__ void flash5(const u16* __restrict__ Qp, const u16* __restrict__ Kb,
                       const u16* __restrict__ Vtg,
                       float* __restrict__ pacc, float* __restrict__ pml) {
  const int blk = blockIdx.x;
  const int sp = blk & 1, qt = (blk >> 1) & 15, bh = blk >> 5;
  const int b = bh >> 3, h = bh & 7;
  __shared__ __align__(16) u16 Ks[64 * 96];      // natural [key][96]
  __shared__ __align__(16) u16 Vs[96 * 64];      // [d][64 keys], chunk-swizzled by d&7
  __shared__ __align__(16) u16 Pl[4 * 16 * 64];  // per-wave [16 q][64 keys], 8B-chunk swz
  const int tid = threadIdx.x, w = tid >> 6, lane = tid & 63;
  const int c = lane & 15, g = lane >> 4;
  const u16* qb = Qp + ((size_t)(b * 1024 + qt * 64 + w * 16 + c)) * 768 + h * 96;
  bf16x8 qf[3];
  #pragma unroll
  for (int kc = 0; kc < 3; ++kc)
    qf[kc] = *reinterpret_cast<const bf16x8*>(qb + kc * 32 + g * 8);
  int koff[3], voff[3], loff[3];
  #pragma unroll
  for (int j = 0; j < 3; ++j) {
    int p = w * 192 + j * 64 + lane;    // 0..767
    int r = p / 12, ch = p - r * 12;
    koff[j] = r * 768 + ch * 8;
    int d = p >> 3, vch = p & 7;
    voff[j] = d * 4096 + ((vch ^ (d & 7)) * 8);
    loff[j] = (w * 192 + j * 64) * 8;
  }
  const u16* kb0 = Kb + ((size_t)(b * 4096 + sp * 2048)) * 768 + h * 96;
  const u16* vb0 = Vtg + ((size_t)(bh * 96)) * 4096 + sp * 2048;
  float m = -1e30f, l = 0.f;
  f32x4 acc[6] = {};
  const int sw = (c & 7) << 3;
  const int psw = (c & 7) << 1;
  const int pbase = w * 1024 + c * 64;
  for (int kt = 0; kt < 32; ++kt) {
    __syncthreads();
    #pragma unroll
    for (int j = 0; j < 3; ++j) gld16(kb0 + (size_t)kt * 49152 + koff[j], &Ks[loff[j]]);
    #pragma unroll
    for (int j = 0; j < 3; ++j) gld16(vb0 + kt * 64 + voff[j], &Vs[loff[j]]);
    __syncthreads();
    f32x4 st[4] = {};
    #pragma unroll
    for (int kc = 0; kc < 3; ++kc)
      #pragma unroll
      for (int kt4 = 0; kt4 < 4; ++kt4) {
        bf16x8 kf = *reinterpret_cast<const bf16x8*>(&Ks[(kt4 * 16 + c) * 96 + kc * 32 + g * 8]);
        st[kt4] = MFMA16(kf, qf[kc], st[kt4]);
      }
    float pmax = st[0][0];
    #pragma unroll
    for (int kt4 = 0; kt4 < 4; ++kt4)
      #pragma unroll
      for (int i = 0; i < 4; ++i)
        pmax = fmaxf(pmax, st[kt4][i]);
    pmax = fmaxf(pmax, __shfl_xor(pmax, 16));
    pmax = fmaxf(pmax, __shfl_xor(pmax, 32));
    if (__any(pmax > m + 8.0f)) {
      float mn = fmaxf(m, pmax);
      float esc = exp2f(m - mn);
      m = mn;
      l *= esc;
      float er[4];
      #pragma unroll
      for (int i = 0; i < 4; ++i) er[i] = __shfl(esc, g * 4 + i);
      #pragma unroll
      for (int dc = 0; dc < 6; ++dc)
        #pragma unroll
        for (int i = 0; i < 4; ++i)
          acc[dc][i] *= er[i];
    }
    float ps = 0.f;
    #pragma unroll
    for (int kt4 = 0; kt4 < 4; ++kt4)
      #pragma unroll
      for (int i = 0; i < 4; ++i) {
        float p = exp2f(st[kt4][i] - m);
        st[kt4][i] = p;
        ps += p;
      }
    ps += __shfl_xor(ps, 16);
    ps += __shfl_xor(ps, 32);
    l += ps;
    #pragma unroll
    for (int kt4 = 0; kt4 < 4; ++kt4) {
      unsigned int u0, u1;
      asm("v_cvt_pk_bf16_f32 %0, %1, %2" : "=v"(u0) : "v"(st[kt4][0]), "v"(st[kt4][1]));
      asm("v_cvt_pk_bf16_f32 %0, %1, %2" : "=v"(u1) : "v"(st[kt4][2]), "v"(st[kt4][3]));
      const int chunk = (kt4 * 4 + g) ^ psw;
      *reinterpret_cast<uint2*>(&Pl[pbase + chunk * 4]) = make_uint2(u0, u1);
    }
    asm volatile("s_waitcnt lgkmcnt(0)" ::: "memory");
    #pragma unroll
    for (int kh = 0; kh < 2; ++kh) {
      const int rchunk = (kh * 8 + g * 2) ^ psw;
      bf16x8 pf = *reinterpret_cast<const bf16x8*>(&Pl[pbase + rchunk * 4]);
      #pragma unroll
      for (int dc = 0; dc < 6; ++dc) {
        bf16x8 vf = *reinterpret_cast<const bf16x8*>(&Vs[(dc * 16 + c) * 64 + ((kh * 32 + g * 8) ^ sw)]);
        acc[dc] = MFMA16(pf, vf, acc[dc]);
      }
    }
  }
  const int prow = blk * 64 + w * 16;
  #pragma unroll
  for (int dc = 0; dc < 6; ++dc)
    #pragma unroll
    for (int i = 0; i < 4; ++i)
      pacc[(size_t)(prow + g * 4 + i) * 96 + dc * 16 + c] = acc[dc][i];
  if (lane < 16) {
    pml[(prow + lane) * 2]     = m;
    pml[(prow + lane) * 2 + 1] = l;
  }
}

// ---------------- combine 2 key-splits -> aout (bf16) ----------------
__global__ void fcomb(const float* __restrict__ pacc, const float* __restrict__ pml,
                      u16* __restrict__ aout) {
  const int bhqt = blockIdx.x;          // 512
  const int qt = bhqt & 15, bh = bhqt >> 4;
  const int b = bh >> 3, h = bh & 7;
  const int p0 = bhqt * 2, p1 = p0 + 1;
  const int tid = threadIdx.x;
  #pragma unroll
  for (int j = 0; j < 6; ++j) {
    int idx = tid + 256 * j;            // 0..1535 f32x4 chunks
    int r = idx / 24, dq = idx - r * 24;
    float m0 = pml[(p0 * 64 + r) * 2], l0 = pml[(p0 * 64 + r) * 2 + 1];
    float m1 = pml[(p1 * 64 + r) * 2], l1 = pml[(p1 * 64 + r) * 2 + 1];
    float M = fmaxf(m0, m1);
    float e0 = exp2f(m0 - M), e1 = exp2f(m1 - M);
    float inv = 1.f / (l0 * e0 + l1 * e1);
    f32x4 a0 = *reinterpret_cast<const f32x4*>(pacc + ((size_t)(p0 * 64 + r)) * 96 + dq * 4);
    f32x4 a1 = *reinterpret_cast<const f32x4*>(pacc + ((size_t)(p1 * 64 + r)) * 96 + dq * 4);
    ushort4 o;
    o.x = f2bf((a0[0] * e0 + a1[0] * e1) * inv);
    o.y = f2bf((a0[1] * e0 + a1[1] * e1) * inv);
    o.z = f2bf((a0[2] * e0 + a1[2] * e1) * inv);
    o.w = f2bf((a0[3] * e0 + a1[3] * e1) * inv);
    *reinterpret_cast<ushort4*>(aout + (size_t)(b * 1024 + qt * 64 + r) * 768 + h * 96 + dq * 4) = o;
  }
}

extern "C" void kernel_launch(void* const* d_in, const int* in_sizes, int n_in,
                              void* d_out, int out_size, void* d_ws, size_t ws_size,
                              hipStream_t stream) {
  const float* hs     = (const float*)d_in[0];
  const float* qkv_w  = (const float*)d_in[1];
  const float* qkv_b  = (const float*)d_in[2];
  const float* proj_w = (const float*)d_in[3];
  const float* proj_b = (const float*)d_in[4];
  float* out = (float*)d_out;

  u16* hs_bf  = (u16*)d_ws;                 // 6291456 u16 (dead after gemm<0>) -> pml
  u16* qkvwT  = hs_bf  + 6291456;           // 884736
  u16* projwT = qkvwT  + 884736;            // 589824
  u16* qfull  = projwT + 589824;            // 12582912 (dead after qpool) -> vT
  u16* kbuf   = qfull  + 12582912;          // 12582912
  u16* vbuf   = kbuf   + 12582912;          // 12582912 (dead after vtrans) -> pacc
  u16* qpol   = vbuf   + 12582912;          // 3145728
  u16* aout   = qpol   + 3145728;           // 3145728

  u16* vT     = qfull;                      // 32*96*4096 = 12582912 u16, exact fit
  float* pacc = (float*)vbuf;               // 1024*64*96*4B = 25165824 B, exact fit
  float* pml  = (float*)hs_bf;              // 524288 B

  cast4<<<6144, 256, 0, stream>>>(hs, hs_bf, 1572864);
  ttrans<<<216, 256, 0, stream>>>(qkv_w, qkvwT, 384, 2304);   // (384/64)*(2304/64)
  ttrans<<<144, 256, 0, stream>>>(proj_w, projwT, 768, 768);  // (768/64)*(768/64)

  gemm_bt<0><<<2304, 256, 0, stream>>>(hs_bf, qkvwT, qkv_b,
                                       qfull, kbuf, vbuf, nullptr, 384, 18, 288);
  qpool<<<1536, 256, 0, stream>>>(qfull, qpol);
  vtrans<<<2048, 256, 0, stream>>>(vbuf, vT);
  flash5<<<1024, 256, 0, stream>>>(qpol, kbuf, vT, pacc, pml);
  fcomb<<<512, 256, 0, stream>>>(pacc, pml, aout);
  gemm_bt<1><<<192, 256, 0, stream>>>(aout, projwT, proj_b,
                                      nullptr, nullptr, nullptr, out, 768, 6, 24);
}